// Round 10
// baseline (786.299 us; speedup 1.0000x reference)
//
#include <hip/hip_runtime.h>

#define BB 32
#define CC 129
#define TT 1000
#define DD 256
#define NN 64
#define NLY 4

// ---------------- workspace layout (floats) ----------------
#define OFF_H    0
#define OFF_K    8192000
#define OFF_INV  9232384
#define OFF_MHA  9264384

typedef __attribute__((ext_vector_type(8))) short bf16x8;
typedef __attribute__((ext_vector_type(4))) float f32x4;
typedef __attribute__((ext_vector_type(16))) float f32x16;

__device__ __forceinline__ unsigned short f2bf(float x) {
    unsigned int u = __float_as_uint(x);
    unsigned int r = (u + 0x7FFF + ((u >> 16) & 1)) >> 16;
    return (unsigned short)r;
}
__device__ __forceinline__ float bf2f(unsigned short b) {
    return __uint_as_float(((unsigned int)b) << 16);
}

// ============ Ad build (block 0) + w_in split-bf16 prep (blocks 1..64) ============
#define ST 131
__global__ __launch_bounds__(1024) void k_build_ad(const float* __restrict__ logdt,
                                                   float* __restrict__ P,
                                                   const float* __restrict__ w_in,
                                                   unsigned short* __restrict__ whi,
                                                   unsigned short* __restrict__ wlo) {
    __shared__ float M[64 * ST + 16];
    int tid = threadIdx.x;
    if (blockIdx.x != 0) {
        int d = (blockIdx.x - 1) * 4 + (tid >> 8);
        int c = tid & 255;
        if (c < 136) {
            float v = (c < CC) ? w_in[d * CC + c] : 0.f;
            unsigned short h = f2bf(v);
            whi[d * 136 + c] = h;
            wlo[d * 136 + c] = f2bf(v - bf2f(h));
        }
        return;
    }
    int q = tid >> 6, r = tid & 63;
    float dt = expf(logdt[0]);
    dt = fminf(fmaxf(dt, 1e-4f), 0.1f);
    float hh = dt * 0.5f;
    float Pr = sqrtf(1.f + 2.f * (float)r);
    for (int j = q; j < 130; j += 16) {
        if (j < 64) {
            float a;
            if (r == j) a = -((float)r + 0.5f);
            else { float m = Pr * sqrtf(1.f + 2.f * (float)j); a = (r > j) ? -m : m; }
            M[r * ST + j] = ((r == j) ? 1.f : 0.f) - hh * a;
        } else {
            M[r * ST + j] = (r == (j - 64)) ? 2.f : 0.f;
        }
    }
    __syncthreads();
    for (int c = 0; c < 64; ++c) {
        float invp = 1.f / M[c * ST + c];
        float f = M[r * ST + c] * invp;
        if (r != c) {
            int j0 = (c + 1) + ((q - (c + 1)) & 15);
            const float* prow = &M[c * ST];
            float* mrow = &M[r * ST];
            for (int j = j0; j < 130; j += 16)
                mrow[j] = fmaf(-f, prow[j], mrow[j]);
        }
        __syncthreads();
    }
    float invd = 1.f / M[r * ST + r];
    for (int j = q; j < 64; j += 16) {
        P[r * 64 + j] = (r == j) ? 1.f : 0.f;
        P[4096 + r * 64 + j] = M[r * ST + 64 + j] * invd - ((r == j) ? 1.f : 0.f);
    }
}

// ============ power-tree matmul; optional Q0/Q1 fold-in on the j==32 block ============
__global__ __launch_bounds__(256) void k_mm64(float* __restrict__ base, int half,
                                              float* __restrict__ qdst) {
    __shared__ float As[4096], Bs[4096];
    int j = half + 1 + blockIdx.x;
    const float* Am = base + (size_t)half * 4096;
    const float* Bm = base + (size_t)(j - half) * 4096;
    float* Dm = base + (size_t)j * 4096;
    for (int i = threadIdx.x; i < 4096; i += 256) { As[i] = Am[i]; Bs[i] = Bm[i]; }
    __syncthreads();
    int tr = (threadIdx.x >> 4) << 2;
    int tc = (threadIdx.x & 15) << 2;
    float acc[4][4];
#pragma unroll
    for (int u = 0; u < 4; ++u)
#pragma unroll
        for (int v = 0; v < 4; ++v) acc[u][v] = 0.f;
    for (int k = 0; k < 64; ++k) {
        float a0 = As[(tr + 0) * 64 + k], a1 = As[(tr + 1) * 64 + k];
        float a2 = As[(tr + 2) * 64 + k], a3 = As[(tr + 3) * 64 + k];
        float b0 = Bs[k * 64 + tc + 0], b1 = Bs[k * 64 + tc + 1];
        float b2 = Bs[k * 64 + tc + 2], b3 = Bs[k * 64 + tc + 3];
        acc[0][0] = fmaf(a0, b0, acc[0][0]); acc[0][1] = fmaf(a0, b1, acc[0][1]);
        acc[0][2] = fmaf(a0, b2, acc[0][2]); acc[0][3] = fmaf(a0, b3, acc[0][3]);
        acc[1][0] = fmaf(a1, b0, acc[1][0]); acc[1][1] = fmaf(a1, b1, acc[1][1]);
        acc[1][2] = fmaf(a1, b2, acc[1][2]); acc[1][3] = fmaf(a1, b3, acc[1][3]);
        acc[2][0] = fmaf(a2, b0, acc[2][0]); acc[2][1] = fmaf(a2, b1, acc[2][1]);
        acc[2][2] = fmaf(a2, b2, acc[2][2]); acc[2][3] = fmaf(a2, b3, acc[2][3]);
        acc[3][0] = fmaf(a3, b0, acc[3][0]); acc[3][1] = fmaf(a3, b1, acc[3][1]);
        acc[3][2] = fmaf(a3, b2, acc[3][2]); acc[3][3] = fmaf(a3, b3, acc[3][3]);
    }
#pragma unroll
    for (int u = 0; u < 4; ++u)
#pragma unroll
        for (int v = 0; v < 4; ++v) Dm[(tr + u) * 64 + tc + v] = acc[u][v];
    if (qdst && j == 32) {
#pragma unroll
        for (int u = 0; u < 4; ++u)
#pragma unroll
            for (int v = 0; v < 4; ++v) {
                int rr = tr + u, cc = tc + v;
                qdst[rr * 64 + cc] = (rr == cc) ? 1.f : 0.f;
                qdst[4096 + rr * 64 + cc] = acc[u][v];
            }
    }
}

// ============ L / R ============
__global__ __launch_bounds__(256) void k_lr(const float* __restrict__ P, const float* __restrict__ Q,
                                            const float* __restrict__ s4B, const float* __restrict__ s4C,
                                            float* __restrict__ L, float* __restrict__ R) {
    __shared__ float Ms[4096];
    int l = blockIdx.x >> 6, rem = blockIdx.x & 63, which = rem >> 5, idx = rem & 31;
    const float* M = which ? (P + (size_t)idx * 4096)
                           : (Q + (size_t)idx * 4096);
    for (int i = threadIdx.x; i < 4096; i += 256) Ms[i] = M[i];
    __syncthreads();
    int d = threadIdx.x;
    if (which == 0) {
        float* dst = L + (((size_t)(l * DD + d) * 32 + idx) * 64);
        for (int jc = 0; jc < 8; ++jc) {
            float acc[8];
#pragma unroll
            for (int u = 0; u < 8; ++u) acc[u] = 0.f;
            for (int i = 0; i < 64; ++i) {
                float bv = s4B[(l * NN + i) * DD + d];
#pragma unroll
                for (int u = 0; u < 8; ++u)
                    acc[u] = fmaf(bv, Ms[i * 64 + jc * 8 + u], acc[u]);
            }
#pragma unroll
            for (int u = 0; u < 8; ++u) dst[jc * 8 + u] = acc[u];
        }
    } else {
        float* dst = R + (((size_t)(l * DD + d) * 32 + idx) * 64);
        const float* Cp = s4C + (size_t)(l * DD + d) * NN;
        for (int ic = 0; ic < 8; ++ic) {
            float acc[8];
#pragma unroll
            for (int u = 0; u < 8; ++u) acc[u] = 0.f;
            for (int j = 0; j < 64; ++j) {
                float cv = Cp[j];
#pragma unroll
                for (int u = 0; u < 8; ++u)
                    acc[u] = fmaf(Ms[(ic * 8 + u) * 64 + j], cv, acc[u]);
            }
#pragma unroll
            for (int u = 0; u < 8; ++u) dst[ic * 8 + u] = acc[u];
        }
    }
}

// ============ kernel assembly ============
__global__ __launch_bounds__(256) void k_kker(const float* __restrict__ L, const float* __restrict__ R,
                                              float* __restrict__ kk) {
    __shared__ float Ls[32 * 65], Rs[32 * 65];
    int l = blockIdx.x >> 8, d = blockIdx.x & 255;
    const float* Lp = L + ((size_t)(l * DD + d) * 32) * 64;
    const float* Rp = R + ((size_t)(l * DD + d) * 32) * 64;
    for (int i = threadIdx.x; i < 2048; i += 256) {
        int row = i >> 6, col = i & 63;
        Ls[row * 65 + col] = Lp[i];
        Rs[row * 65 + col] = Rp[i];
    }
    __syncthreads();
    for (int t = threadIdx.x; t < TT; t += 256) {
        int kq = t >> 5, r = t & 31;
        const float* lr = &Ls[kq * 65];
        const float* rr = &Rs[r * 65];
        float a = 0.f;
#pragma unroll 8
        for (int m = 0; m < 64; ++m) a = fmaf(lr[m], rr[m], a);
        kk[(size_t)(l * DD + d) * TT + t] = a * expf(-0.01f * (float)t);
    }
}

// ============ MFMA embed + fused LayerNorm + pos-encoding + invn ============
__global__ __launch_bounds__(256) void k_embed_mfma(const float* __restrict__ x,
                                                    const unsigned short* __restrict__ whi,
                                                    const unsigned short* __restrict__ wlo,
                                                    const float* __restrict__ w_in,
                                                    const float* __restrict__ b_in,
                                                    const float* __restrict__ lng,
                                                    const float* __restrict__ lnb,
                                                    float* __restrict__ h,
                                                    float* __restrict__ invn) {
    __shared__ unsigned short xs_h[64 * 130], xs_l[64 * 130];
    __shared__ float xlasts[64], w128s[256], biass[256], gs[256], bs[256];
    __shared__ float ps[64][16], ps2[64][16];
    __shared__ float mstat[64], rstat[64];
    int b = blockIdx.y, t0 = blockIdx.x * 64;
    int tid = threadIdx.x;
    for (int i = tid; i < CC * 64; i += 256) {
        int c = i >> 6, tl = i & 63;
        int t = t0 + tl;
        float v = (t < TT) ? x[(size_t)(b * CC + c) * TT + t] : 0.f;
        if (c == 128) {
            xlasts[tl] = v;
        } else {
            unsigned short hh = f2bf(v);
            xs_h[tl * 130 + c] = hh;
            xs_l[tl * 130 + c] = f2bf(v - bf2f(hh));
        }
    }
    w128s[tid] = w_in[tid * CC + 128];
    biass[tid] = b_in[tid];
    gs[tid] = lng[tid];
    bs[tid] = lnb[tid];
    __syncthreads();
    int wave = tid >> 6, lane = tid & 63;
    int tn = lane & 15, q = lane >> 4;
    int d0w = wave * 64;
    f32x4 acc[4][4];
#pragma unroll
    for (int nt = 0; nt < 4; ++nt)
#pragma unroll
        for (int mt = 0; mt < 4; ++mt) acc[nt][mt] = (f32x4){0.f, 0.f, 0.f, 0.f};
#pragma unroll
    for (int kc = 0; kc < 4; ++kc) {
        int c0 = kc * 32;
        bf16x8 Ah[4], Al[4];
#pragma unroll
        for (int mt = 0; mt < 4; ++mt) {
            int base = (d0w + mt * 16 + tn) * 136 + c0 + 8 * q;
            Ah[mt] = *(const bf16x8*)&whi[base];
            Al[mt] = *(const bf16x8*)&wlo[base];
        }
#pragma unroll
        for (int nt = 0; nt < 4; ++nt) {
            const unsigned int* ph = (const unsigned int*)&xs_h[(nt * 16 + tn) * 130 + c0 + 8 * q];
            const unsigned int* pl = (const unsigned int*)&xs_l[(nt * 16 + tn) * 130 + c0 + 8 * q];
            union { bf16x8 v; unsigned int u[4]; } Bh, Bl;
            Bh.u[0] = ph[0]; Bh.u[1] = ph[1]; Bh.u[2] = ph[2]; Bh.u[3] = ph[3];
            Bl.u[0] = pl[0]; Bl.u[1] = pl[1]; Bl.u[2] = pl[2]; Bl.u[3] = pl[3];
#pragma unroll
            for (int mt = 0; mt < 4; ++mt) {
                acc[nt][mt] = __builtin_amdgcn_mfma_f32_16x16x32_bf16(Al[mt], Bh.v, acc[nt][mt], 0, 0, 0);
                acc[nt][mt] = __builtin_amdgcn_mfma_f32_16x16x32_bf16(Ah[mt], Bl.v, acc[nt][mt], 0, 0, 0);
                acc[nt][mt] = __builtin_amdgcn_mfma_f32_16x16x32_bf16(Ah[mt], Bh.v, acc[nt][mt], 0, 0, 0);
            }
        }
    }
#pragma unroll
    for (int nt = 0; nt < 4; ++nt) {
        float xl = xlasts[nt * 16 + tn];
        float s = 0.f, s2 = 0.f;
#pragma unroll
        for (int mt = 0; mt < 4; ++mt) {
#pragma unroll
            for (int r = 0; r < 4; ++r) {
                int d = d0w + mt * 16 + 4 * q + r;
                float v = acc[nt][mt][r] + biass[d] + w128s[d] * xl;
                acc[nt][mt][r] = v;
                s += v; s2 = fmaf(v, v, s2);
            }
        }
        ps[nt * 16 + tn][wave * 4 + q] = s;
        ps2[nt * 16 + tn][wave * 4 + q] = s2;
    }
    __syncthreads();
    if (tid < 64) {
        float s = 0.f, s2 = 0.f;
#pragma unroll
        for (int k = 0; k < 16; ++k) { s += ps[tid][k]; s2 += ps2[tid][k]; }
        float mean = s * (1.f / 256.f);
        float ex2 = s2 * (1.f / 256.f);
        mstat[tid] = mean;
        rstat[tid] = 1.f / sqrtf(ex2 - mean * mean + 1e-5f);
    }
    __syncthreads();
#pragma unroll
    for (int nt = 0; nt < 4; ++nt) {
        int tl = nt * 16 + tn;
        int t = t0 + tl;
        float mean = mstat[tl], rstd = rstat[tl];
        float ft = (float)t;
        float sq = 0.f;
#pragma unroll
        for (int mt = 0; mt < 4; ++mt) {
#pragma unroll
            for (int r = 0; r < 4; ++r) {
                int d = d0w + mt * 16 + 4 * q + r;
                float o = (acc[nt][mt][r] - mean) * rstd * gs[d] + bs[d];
                float freq = expf((float)(d & ~1) * (-9.210340371976184f / 256.f));
                float ang = ft * freq;
                o += (d & 1) ? cosf(ang) : sinf(ang);
                if (t < TT) h[((size_t)(b * DD + d)) * TT + t] = o;
                sq = fmaf(o, o, sq);
            }
        }
        ps[tl][wave * 4 + q] = sq;
    }
    __syncthreads();
    if (tid < 64) {
        int t = t0 + tid;
        if (t < TT) {
            float s = 0.f;
#pragma unroll
            for (int k = 0; k < 16; ++k) s += ps[tid][k];
            invn[b * TT + t] = 1.f / (sqrtf(s) + 1e-8f);
        }
    }
}

// ============ LayerNorm (in-place), single-pass ============
__global__ __launch_bounds__(256) void k_ln(const float* __restrict__ in, const float* __restrict__ g,
                                            const float* __restrict__ bia, float* __restrict__ out,
                                            float* __restrict__ invn) {
    int b = blockIdx.y, t0 = blockIdx.x * 64;
    int w = threadIdx.x >> 6, lane = threadIdx.x & 63;
    int t = t0 + lane;
    __shared__ float ps[4][64], ps2[4][64];
    float v[64];
    float s = 0.f, s2 = 0.f;
    bool ok = t < TT;
#pragma unroll
    for (int k = 0; k < 64; ++k) {
        float x = ok ? in[(size_t)(b * DD + (w + 4 * k)) * TT + t] : 0.f;
        v[k] = x;
        s += x; s2 = fmaf(x, x, s2);
    }
    ps[w][lane] = s; ps2[w][lane] = s2;
    __syncthreads();
    float mean = (ps[0][lane] + ps[1][lane] + ps[2][lane] + ps[3][lane]) * (1.f / 256.f);
    float ex2  = (ps2[0][lane] + ps2[1][lane] + ps2[2][lane] + ps2[3][lane]) * (1.f / 256.f);
    float rstd = 1.f / sqrtf(ex2 - mean * mean + 1e-5f);
    float sq = 0.f;
    if (ok) {
#pragma unroll
        for (int k = 0; k < 64; ++k) {
            int d = w + 4 * k;
            float o = (v[k] - mean) * rstd * g[d] + bia[d];
            out[(size_t)(b * DD + d) * TT + t] = o;
            sq = fmaf(o, o, sq);
        }
    }
    __syncthreads();
    ps[w][lane] = sq;
    __syncthreads();
    if (w == 0 && ok) {
        float tot = ps[0][lane] + ps[1][lane] + ps[2][lane] + ps[3][lane];
        invn[b * TT + t] = 1.f / (sqrtf(tot) + 1e-8f);
    }
}

__device__ __forceinline__ float gelu_exact(float y) {
    return 0.5f * y * (1.f + erff(y * 0.7071067811865476f));
}

// ============ MFMA conv, 32x32x16 (4x less LDS per MAC), one block per d, 32 batches ============
// D-major, 2 adjacent-j members share the wave-uniform Toeplitz B-frag; corrections
// (ah*bl, al*bh) share one accumulator. Snake balance: wave w does groups {w, 15-w}
// -> 68 D-steps per wave. D down to -16 covers each tile's upper triangle (zero-padded).
#define XS2 1032
__global__ __launch_bounds__(512) void k_conv32(float* __restrict__ h, const float* __restrict__ kk,
                                                const float* __restrict__ invn,
                                                const float* __restrict__ s4D, int layer) {
    __shared__ unsigned short Xh[32 * XS2], Xl[32 * XS2];
    __shared__ unsigned int pkh[1056], pkl[1056];
    int d = blockIdx.x;
    int tid = threadIdx.x;
    const float* krow = kk + (size_t)(layer * DD + d) * TT;
    for (int mm = tid; mm < 1056; mm += 512) {
        int m = mm - 32;
        float klo = (m >= 0 && m < TT) ? krow[m] : 0.f;
        float kpr = (m >= 1 && m <= TT) ? krow[m - 1] : 0.f;
        unsigned short lh = f2bf(klo); unsigned short ll = f2bf(klo - bf2f(lh));
        unsigned short ph = f2bf(kpr); unsigned short pl = f2bf(kpr - bf2f(ph));
        pkh[mm] = (unsigned int)lh | ((unsigned int)ph << 16);
        pkl[mm] = (unsigned int)ll | ((unsigned int)pl << 16);
    }
    for (int ii = tid; ii < 32 * 512; ii += 512) {
        int bb = ii >> 9;
        int tp = (ii & 511) * 2;
        const float* hrow = h + ((size_t)bb * DD + d) * TT;
        const float* ivr = invn + (size_t)bb * TT;
        float v0 = (tp < TT) ? hrow[tp] * ivr[tp] : 0.f;
        float v1 = (tp + 1 < TT) ? hrow[tp + 1] * ivr[tp + 1] : 0.f;
        unsigned short h0 = f2bf(v0), l0 = f2bf(v0 - bf2f(h0));
        unsigned short h1 = f2bf(v1), l1 = f2bf(v1 - bf2f(h1));
        ((unsigned int*)Xh)[(bb * XS2 + tp) >> 1] = (unsigned int)h0 | ((unsigned int)h1 << 16);
        ((unsigned int*)Xl)[(bb * XS2 + tp) >> 1] = (unsigned int)l0 | ((unsigned int)l1 << 16);
    }
    __syncthreads();
    float gate = 1.f / (1.f + expf(-s4D[layer * DD + d]));
    int wave = tid >> 6, lane = tid & 63;
    int nn = lane & 31, kq8 = (lane >> 5) << 3;
    for (int pass = 0; pass < 2; ++pass) {
        int G = pass ? (15 - wave) : wave;
        int jlo = 2 * G;
        f32x16 aM[2], aC[2];
#pragma unroll
        for (int m = 0; m < 2; ++m) {
#pragma unroll
            for (int r = 0; r < 16; ++r) { aM[m][r] = 0.f; aC[m][r] = 0.f; }
        }
        for (int D = 32 * jlo + 32; D >= -16; D -= 16) {
            int S32 = D + nn - kq8 + 32;
            union { bf16x8 v; unsigned int u[4]; } bh, bl;
            bh.u[0] = pkh[S32];     bl.u[0] = pkl[S32];
            bh.u[1] = pkh[S32 - 2]; bl.u[1] = pkl[S32 - 2];
            bh.u[2] = pkh[S32 - 4]; bl.u[2] = pkl[S32 - 4];
            bh.u[3] = pkh[S32 - 6]; bl.u[3] = pkl[S32 - 6];
#pragma unroll
            for (int m = 0; m < 2; ++m) {
                int u0 = (jlo + m) * 32 - D;
                if (u0 >= 0) {
                    const bf16x8 ah = *(const bf16x8*)&Xh[nn * XS2 + u0 + kq8];
                    const bf16x8 al = *(const bf16x8*)&Xl[nn * XS2 + u0 + kq8];
                    aM[m] = __builtin_amdgcn_mfma_f32_32x32x16_bf16(ah, bh.v, aM[m], 0, 0, 0);
                    aC[m] = __builtin_amdgcn_mfma_f32_32x32x16_bf16(ah, bl.v, aC[m], 0, 0, 0);
                    aC[m] = __builtin_amdgcn_mfma_f32_32x32x16_bf16(al, bh.v, aC[m], 0, 0, 0);
                }
            }
        }
#pragma unroll
        for (int m = 0; m < 2; ++m) {
            int t = (jlo + m) * 32 + nn;
            if (t < TT) {
#pragma unroll
                for (int r = 0; r < 16; ++r) {
                    int brow = (r & 3) + 8 * (r >> 2) + 4 * (lane >> 5);
                    size_t ix = ((size_t)brow * DD + d) * TT + t;
                    float y = aM[m][r] + aC[m][r];
                    float xn = bf2f(Xh[brow * XS2 + t]) + bf2f(Xl[brow * XS2 + t]);
                    float ho = xn * __builtin_amdgcn_rcpf(invn[brow * TT + t]);
                    h[ix] = gelu_exact(y + xn * gate) + 1.1f * ho;
                }
            }
        }
    }
}

// ============ MHA pooling ============
__global__ __launch_bounds__(256) void k_qprep(const float* __restrict__ cls, const float* __restrict__ inw,
                                               const float* __restrict__ inb, float* __restrict__ qk,
                                               float* __restrict__ qb) {
    __shared__ float Qv[256];
    int j = threadIdx.x;
    float a = inb[j];
    for (int i = 0; i < 256; ++i) a = fmaf(inw[j * DD + i], cls[i], a);
    Qv[j] = a;
    __syncthreads();
    const float scale = 0.17677669529663687f; // 1/sqrt(32)
    for (int idx = threadIdx.x; idx < 8 * 256; idx += 256) {
        int hh = idx >> 8, i = idx & 255;
        float s = 0.f;
        for (int jj = 0; jj < 32; ++jj)
            s = fmaf(Qv[hh * 32 + jj], inw[(DD + hh * 32 + jj) * DD + i], s);
        qk[idx] = s * scale;
    }
    if (threadIdx.x < 8) {
        int hh = threadIdx.x;
        float s = 0.f;
        for (int jj = 0; jj < 32; ++jj)
            s = fmaf(Qv[hh * 32 + jj], inb[DD + hh * 32 + jj], s);
        qb[hh] = s * scale;
    }
}

__global__ __launch_bounds__(256) void k_scores(const float* __restrict__ h, const float* __restrict__ cls,
                                                const float* __restrict__ qkw, const float* __restrict__ qbw,
                                                float* __restrict__ sc) {
    __shared__ float qks[8 * 256];
    int b = blockIdx.y;
    int s = blockIdx.x * 256 + threadIdx.x;
    for (int i = threadIdx.x; i < 2048; i += 256) qks[i] = qkw[i];
    __syncthreads();
    if (s >= TT + 1) return;
    float acc[8];
#pragma unroll
    for (int hh = 0; hh < 8; ++hh) acc[hh] = qbw[hh];
    if (s == 0) {
        for (int i = 0; i < 256; ++i) {
            float v = cls[i];
#pragma unroll
            for (int hh = 0; hh < 8; ++hh) acc[hh] = fmaf(qks[hh * 256 + i], v, acc[hh]);
        }
    } else {
        const float* hb = h + (size_t)b * DD * TT + (s - 1);
        for (int i = 0; i < 256; ++i) {
            float v = hb[(size_t)i * TT];
#pragma unroll
            for (int hh = 0; hh < 8; ++hh) acc[hh] = fmaf(qks[hh * 256 + i], v, acc[hh]);
        }
    }
#pragma unroll
    for (int hh = 0; hh < 8; ++hh) sc[(size_t)(b * 8 + hh) * 1024 + s] = acc[hh];
}

__global__ __launch_bounds__(256) void k_softmax(const float* __restrict__ sc, float* __restrict__ att) {
    int row = blockIdx.x;
    const float* p = sc + (size_t)row * 1024;
    float* o = att + (size_t)row * 1024;
    __shared__ float red[256];
    float m = -3.4e38f;
    for (int s = threadIdx.x; s < TT + 1; s += 256) m = fmaxf(m, p[s]);
    red[threadIdx.x] = m; __syncthreads();
    for (int st = 128; st; st >>= 1) {
        if (threadIdx.x < st) red[threadIdx.x] = fmaxf(red[threadIdx.x], red[threadIdx.x + st]);
        __syncthreads();
    }
    m = red[0]; __syncthreads();
    float sum = 0.f;
    for (int s = threadIdx.x; s < TT + 1; s += 256) {
        float e = expf(p[s] - m);
        o[s] = e; sum += e;
    }
    red[threadIdx.x] = sum; __syncthreads();
    for (int st = 128; st; st >>= 1) {
        if (threadIdx.x < st) red[threadIdx.x] += red[threadIdx.x + st];
        __syncthreads();
    }
    float inv = 1.f / red[0];
    for (int s = threadIdx.x; s < TT + 1; s += 256) o[s] *= inv;
}

__global__ __launch_bounds__(256) void k_ctx(const float* __restrict__ h, const float* __restrict__ cls,
                                             const float* __restrict__ att, float* __restrict__ ctx) {
    __shared__ float as[8][1024];
    int b = blockIdx.y, i0 = blockIdx.x * 32;
    for (int idx = threadIdx.x; idx < 8 * 1024; idx += 256) {
        int hh = idx >> 10, s = idx & 1023;
        as[hh][s] = (s < TT + 1) ? att[(size_t)(b * 8 + hh) * 1024 + s] : 0.f;
    }
    __syncthreads();
    int w = threadIdx.x >> 6, lane = threadIdx.x & 63;
    for (int ii = 0; ii < 8; ++ii) {
        int i = i0 + w * 8 + ii;
        const float* hb = h + (size_t)(b * DD + i) * TT;
        float acc[8];
#pragma unroll
        for (int hh = 0; hh < 8; ++hh) acc[hh] = 0.f;
        for (int t = lane; t < TT; t += 64) {
            float v = hb[t];
#pragma unroll
            for (int hh = 0; hh < 8; ++hh) acc[hh] = fmaf(as[hh][t + 1], v, acc[hh]);
        }
#pragma unroll
        for (int off = 32; off; off >>= 1)
#pragma unroll
            for (int hh = 0; hh < 8; ++hh) acc[hh] += __shfl_down(acc[hh], off);
        if (lane == 0) {
#pragma unroll
            for (int hh = 0; hh < 8; ++hh)
                ctx[(size_t)(b * 8 + hh) * DD + i] = acc[hh] + as[hh][0] * cls[i];
        }
    }
}

__global__ __launch_bounds__(256) void k_head(const float* __restrict__ ctx, const float* __restrict__ inw,
                                              const float* __restrict__ inb, const float* __restrict__ outw,
                                              const float* __restrict__ outb, const float* __restrict__ w1,
                                              const float* __restrict__ b1, const float* __restrict__ w2,
                                              const float* __restrict__ b2, float* __restrict__ out) {
    int b = blockIdx.x;
    __shared__ float cs[2048], ao[256], po[256], hid[128];
    for (int i = threadIdx.x; i < 2048; i += 256) cs[i] = ctx[(size_t)b * 2048 + i];
    __syncthreads();
    int j = threadIdx.x;
    {
        int hh = j >> 5;
        float a = inb[2 * DD + j];
        const float* wv = inw + (size_t)(2 * DD + j) * DD;
        for (int i = 0; i < 256; ++i) a = fmaf(wv[i], cs[hh * 256 + i], a);
        ao[j] = a;
    }
    __syncthreads();
    {
        float a = outb[j];
        for (int i = 0; i < 256; ++i) a = fmaf(outw[j * DD + i], ao[i], a);
        po[j] = a;
    }
    __syncthreads();
    if (j < 128) {
        float a = b1[j];
        for (int i = 0; i < 256; ++i) a = fmaf(w1[j * 256 + i], po[i], a);
        hid[j] = fmaxf(a, 0.f);
    }
    __syncthreads();
    if (j == 0) {
        float a = b2[0];
        for (int i = 0; i < 128; ++i) a = fmaf(w2[i], hid[i], a);
        out[b] = a;
    }
}

extern "C" void kernel_launch(void* const* d_in, const int* in_sizes, int n_in,
                              void* d_out, int out_size, void* d_ws, size_t ws_size,
                              hipStream_t stream) {
    (void)in_sizes; (void)n_in; (void)out_size; (void)ws_size;
    const float* x        = (const float*)d_in[0];
    const float* w_in     = (const float*)d_in[1];
    const float* b_in     = (const float*)d_in[2];
    const float* ln_in_g  = (const float*)d_in[3];
    const float* ln_in_b  = (const float*)d_in[4];
    const float* s4B      = (const float*)d_in[5];
    const float* s4C      = (const float*)d_in[6];
    const float* s4logdt  = (const float*)d_in[7];
    const float* s4D      = (const float*)d_in[8];
    const float* ln_g     = (const float*)d_in[9];
    const float* ln_b     = (const float*)d_in[10];
    const float* cls      = (const float*)d_in[11];
    const float* mha_in_w = (const float*)d_in[12];
    const float* mha_in_b = (const float*)d_in[13];
    const float* mha_out_w= (const float*)d_in[14];
    const float* mha_out_b= (const float*)d_in[15];
    const float* head_w1  = (const float*)d_in[16];
    const float* head_b1  = (const float*)d_in[17];
    const float* head_w2  = (const float*)d_in[18];
    const float* head_b2  = (const float*)d_in[19];

    float* ws   = (float*)d_ws;
    float* h    = ws + OFF_H;
    float* kker = ws + OFF_K;
    float* invn = ws + OFF_INV;
    float* P  = h;                 // 33 * 4096
    float* Q  = h + 540672;        // 32 * 4096
    float* Lb = h + 1064960;
    float* Rb = h + 3162112;
    float* qkb  = ws + OFF_MHA;
    float* qbb  = qkb + 2048;
    float* scb  = qbb + 16;
    float* attb = scb + 262144;
    float* ctxb = attb + 262144;
    unsigned short* whi = (unsigned short*)scb;
    unsigned short* wlo = whi + 256 * 136;

    k_build_ad<<<dim3(65), dim3(1024), 0, stream>>>(s4logdt, P, w_in, whi, wlo);
    for (int m = 1; m <= 5; ++m) {
        int half = 1 << (m - 1);
        k_mm64<<<dim3(half), dim3(256), 0, stream>>>(P, half, (m == 5) ? Q : nullptr);
    }
    for (int m = 1; m <= 5; ++m) {
        int half = 1 << (m - 1);
        int cnt = (m == 5) ? 15 : half;
        k_mm64<<<dim3(cnt), dim3(256), 0, stream>>>(Q, half, nullptr);
    }
    k_lr<<<dim3(NLY * 64), dim3(256), 0, stream>>>(P, Q, s4B, s4C, Lb, Rb);
    k_kker<<<dim3(NLY * 256), dim3(256), 0, stream>>>(Lb, Rb, kker);

    k_embed_mfma<<<dim3(16, BB), dim3(256), 0, stream>>>(x, whi, wlo, w_in, b_in,
                                                         ln_in_g, ln_in_b, h, invn);

    for (int l = 0; l < NLY; ++l) {
        k_conv32<<<dim3(DD), dim3(512), 0, stream>>>(h, kker, invn, s4D, l);
        k_ln<<<dim3(16, BB), dim3(256), 0, stream>>>(h, ln_g + l * DD, ln_b + l * DD, h, invn);
    }

    k_qprep<<<dim3(1), dim3(256), 0, stream>>>(cls, mha_in_w, mha_in_b, qkb, qbb);
    k_scores<<<dim3(4, BB), dim3(256), 0, stream>>>(h, cls, qkb, qbb, scb);
    k_softmax<<<dim3(256), dim3(256), 0, stream>>>(scb, attb);
    k_ctx<<<dim3(8, BB), dim3(256), 0, stream>>>(h, cls, attb, ctxb);
    k_head<<<dim3(BB), dim3(256), 0, stream>>>(ctxb, mha_in_w, mha_in_b, mha_out_w, mha_out_b,
                                               head_w1, head_b1, head_w2, head_b2, (float*)d_out);
}

// Round 11
// 678.922 us; speedup vs baseline: 1.1582x; 1.1582x over previous
//
#include <hip/hip_runtime.h>

#define BB 32
#define CC 129
#define TT 1000
#define DD 256
#define NN 64
#define NLY 4

// ---------------- workspace layout (floats) ----------------
#define OFF_H    0
#define OFF_K    8192000
#define OFF_INV  9232384
#define OFF_MHA  9264384

typedef __attribute__((ext_vector_type(8))) short bf16x8;
typedef __attribute__((ext_vector_type(4))) float f32x4;
typedef __attribute__((ext_vector_type(16))) float f32x16;

__device__ __forceinline__ unsigned short f2bf(float x) {
    unsigned int u = __float_as_uint(x);
    unsigned int r = (u + 0x7FFF + ((u >> 16) & 1)) >> 16;
    return (unsigned short)r;
}
__device__ __forceinline__ float bf2f(unsigned short b) {
    return __uint_as_float(((unsigned int)b) << 16);
}

// ============ Ad build (block 0) + w_in split-bf16 prep (blocks 1..64) ============
#define ST 131
__global__ __launch_bounds__(1024) void k_build_ad(const float* __restrict__ logdt,
                                                   float* __restrict__ P,
                                                   const float* __restrict__ w_in,
                                                   unsigned short* __restrict__ whi,
                                                   unsigned short* __restrict__ wlo) {
    __shared__ float M[64 * ST + 16];
    int tid = threadIdx.x;
    if (blockIdx.x != 0) {
        int d = (blockIdx.x - 1) * 4 + (tid >> 8);
        int c = tid & 255;
        if (c < 136) {
            float v = (c < CC) ? w_in[d * CC + c] : 0.f;
            unsigned short h = f2bf(v);
            whi[d * 136 + c] = h;
            wlo[d * 136 + c] = f2bf(v - bf2f(h));
        }
        return;
    }
    int q = tid >> 6, r = tid & 63;
    float dt = expf(logdt[0]);
    dt = fminf(fmaxf(dt, 1e-4f), 0.1f);
    float hh = dt * 0.5f;
    float Pr = sqrtf(1.f + 2.f * (float)r);
    for (int j = q; j < 130; j += 16) {
        if (j < 64) {
            float a;
            if (r == j) a = -((float)r + 0.5f);
            else { float m = Pr * sqrtf(1.f + 2.f * (float)j); a = (r > j) ? -m : m; }
            M[r * ST + j] = ((r == j) ? 1.f : 0.f) - hh * a;
        } else {
            M[r * ST + j] = (r == (j - 64)) ? 2.f : 0.f;
        }
    }
    __syncthreads();
    for (int c = 0; c < 64; ++c) {
        float invp = 1.f / M[c * ST + c];
        float f = M[r * ST + c] * invp;
        if (r != c) {
            int j0 = (c + 1) + ((q - (c + 1)) & 15);
            const float* prow = &M[c * ST];
            float* mrow = &M[r * ST];
            for (int j = j0; j < 130; j += 16)
                mrow[j] = fmaf(-f, prow[j], mrow[j]);
        }
        __syncthreads();
    }
    float invd = 1.f / M[r * ST + r];
    for (int j = q; j < 64; j += 16) {
        P[r * 64 + j] = (r == j) ? 1.f : 0.f;
        P[4096 + r * 64 + j] = M[r * ST + 64 + j] * invd - ((r == j) ? 1.f : 0.f);
    }
}

// ============ power-tree matmul; optional Q0/Q1 fold-in on the j==32 block ============
__global__ __launch_bounds__(256) void k_mm64(float* __restrict__ base, int half,
                                              float* __restrict__ qdst) {
    __shared__ float As[4096], Bs[4096];
    int j = half + 1 + blockIdx.x;
    const float* Am = base + (size_t)half * 4096;
    const float* Bm = base + (size_t)(j - half) * 4096;
    float* Dm = base + (size_t)j * 4096;
    for (int i = threadIdx.x; i < 4096; i += 256) { As[i] = Am[i]; Bs[i] = Bm[i]; }
    __syncthreads();
    int tr = (threadIdx.x >> 4) << 2;
    int tc = (threadIdx.x & 15) << 2;
    float acc[4][4];
#pragma unroll
    for (int u = 0; u < 4; ++u)
#pragma unroll
        for (int v = 0; v < 4; ++v) acc[u][v] = 0.f;
    for (int k = 0; k < 64; ++k) {
        float a0 = As[(tr + 0) * 64 + k], a1 = As[(tr + 1) * 64 + k];
        float a2 = As[(tr + 2) * 64 + k], a3 = As[(tr + 3) * 64 + k];
        float b0 = Bs[k * 64 + tc + 0], b1 = Bs[k * 64 + tc + 1];
        float b2 = Bs[k * 64 + tc + 2], b3 = Bs[k * 64 + tc + 3];
        acc[0][0] = fmaf(a0, b0, acc[0][0]); acc[0][1] = fmaf(a0, b1, acc[0][1]);
        acc[0][2] = fmaf(a0, b2, acc[0][2]); acc[0][3] = fmaf(a0, b3, acc[0][3]);
        acc[1][0] = fmaf(a1, b0, acc[1][0]); acc[1][1] = fmaf(a1, b1, acc[1][1]);
        acc[1][2] = fmaf(a1, b2, acc[1][2]); acc[1][3] = fmaf(a1, b3, acc[1][3]);
        acc[2][0] = fmaf(a2, b0, acc[2][0]); acc[2][1] = fmaf(a2, b1, acc[2][1]);
        acc[2][2] = fmaf(a2, b2, acc[2][2]); acc[2][3] = fmaf(a2, b3, acc[2][3]);
        acc[3][0] = fmaf(a3, b0, acc[3][0]); acc[3][1] = fmaf(a3, b1, acc[3][1]);
        acc[3][2] = fmaf(a3, b2, acc[3][2]); acc[3][3] = fmaf(a3, b3, acc[3][3]);
    }
#pragma unroll
    for (int u = 0; u < 4; ++u)
#pragma unroll
        for (int v = 0; v < 4; ++v) Dm[(tr + u) * 64 + tc + v] = acc[u][v];
    if (qdst && j == 32) {
#pragma unroll
        for (int u = 0; u < 4; ++u)
#pragma unroll
            for (int v = 0; v < 4; ++v) {
                int rr = tr + u, cc = tc + v;
                qdst[rr * 64 + cc] = (rr == cc) ? 1.f : 0.f;
                qdst[4096 + rr * 64 + cc] = acc[u][v];
            }
    }
}

// ============ L / R ============
__global__ __launch_bounds__(256) void k_lr(const float* __restrict__ P, const float* __restrict__ Q,
                                            const float* __restrict__ s4B, const float* __restrict__ s4C,
                                            float* __restrict__ L, float* __restrict__ R) {
    __shared__ float Ms[4096];
    int l = blockIdx.x >> 6, rem = blockIdx.x & 63, which = rem >> 5, idx = rem & 31;
    const float* M = which ? (P + (size_t)idx * 4096)
                           : (Q + (size_t)idx * 4096);
    for (int i = threadIdx.x; i < 4096; i += 256) Ms[i] = M[i];
    __syncthreads();
    int d = threadIdx.x;
    if (which == 0) {
        float* dst = L + (((size_t)(l * DD + d) * 32 + idx) * 64);
        for (int jc = 0; jc < 8; ++jc) {
            float acc[8];
#pragma unroll
            for (int u = 0; u < 8; ++u) acc[u] = 0.f;
            for (int i = 0; i < 64; ++i) {
                float bv = s4B[(l * NN + i) * DD + d];
#pragma unroll
                for (int u = 0; u < 8; ++u)
                    acc[u] = fmaf(bv, Ms[i * 64 + jc * 8 + u], acc[u]);
            }
#pragma unroll
            for (int u = 0; u < 8; ++u) dst[jc * 8 + u] = acc[u];
        }
    } else {
        float* dst = R + (((size_t)(l * DD + d) * 32 + idx) * 64);
        const float* Cp = s4C + (size_t)(l * DD + d) * NN;
        for (int ic = 0; ic < 8; ++ic) {
            float acc[8];
#pragma unroll
            for (int u = 0; u < 8; ++u) acc[u] = 0.f;
            for (int j = 0; j < 64; ++j) {
                float cv = Cp[j];
#pragma unroll
                for (int u = 0; u < 8; ++u)
                    acc[u] = fmaf(Ms[(ic * 8 + u) * 64 + j], cv, acc[u]);
            }
#pragma unroll
            for (int u = 0; u < 8; ++u) dst[ic * 8 + u] = acc[u];
        }
    }
}

// ============ kernel assembly ============
__global__ __launch_bounds__(256) void k_kker(const float* __restrict__ L, const float* __restrict__ R,
                                              float* __restrict__ kk) {
    __shared__ float Ls[32 * 65], Rs[32 * 65];
    int l = blockIdx.x >> 8, d = blockIdx.x & 255;
    const float* Lp = L + ((size_t)(l * DD + d) * 32) * 64;
    const float* Rp = R + ((size_t)(l * DD + d) * 32) * 64;
    for (int i = threadIdx.x; i < 2048; i += 256) {
        int row = i >> 6, col = i & 63;
        Ls[row * 65 + col] = Lp[i];
        Rs[row * 65 + col] = Rp[i];
    }
    __syncthreads();
    for (int t = threadIdx.x; t < TT; t += 256) {
        int kq = t >> 5, r = t & 31;
        const float* lr = &Ls[kq * 65];
        const float* rr = &Rs[r * 65];
        float a = 0.f;
#pragma unroll 8
        for (int m = 0; m < 64; ++m) a = fmaf(lr[m], rr[m], a);
        kk[(size_t)(l * DD + d) * TT + t] = a * expf(-0.01f * (float)t);
    }
}

// ============ MFMA embed + fused LayerNorm + pos-encoding + invn ============
__global__ __launch_bounds__(256) void k_embed_mfma(const float* __restrict__ x,
                                                    const unsigned short* __restrict__ whi,
                                                    const unsigned short* __restrict__ wlo,
                                                    const float* __restrict__ w_in,
                                                    const float* __restrict__ b_in,
                                                    const float* __restrict__ lng,
                                                    const float* __restrict__ lnb,
                                                    float* __restrict__ h,
                                                    float* __restrict__ invn) {
    __shared__ unsigned short xs_h[64 * 130], xs_l[64 * 130];
    __shared__ float xlasts[64], w128s[256], biass[256], gs[256], bs[256];
    __shared__ float ps[64][16], ps2[64][16];
    __shared__ float mstat[64], rstat[64];
    int b = blockIdx.y, t0 = blockIdx.x * 64;
    int tid = threadIdx.x;
    for (int i = tid; i < CC * 64; i += 256) {
        int c = i >> 6, tl = i & 63;
        int t = t0 + tl;
        float v = (t < TT) ? x[(size_t)(b * CC + c) * TT + t] : 0.f;
        if (c == 128) {
            xlasts[tl] = v;
        } else {
            unsigned short hh = f2bf(v);
            xs_h[tl * 130 + c] = hh;
            xs_l[tl * 130 + c] = f2bf(v - bf2f(hh));
        }
    }
    w128s[tid] = w_in[tid * CC + 128];
    biass[tid] = b_in[tid];
    gs[tid] = lng[tid];
    bs[tid] = lnb[tid];
    __syncthreads();
    int wave = tid >> 6, lane = tid & 63;
    int tn = lane & 15, q = lane >> 4;
    int d0w = wave * 64;
    f32x4 acc[4][4];
#pragma unroll
    for (int nt = 0; nt < 4; ++nt)
#pragma unroll
        for (int mt = 0; mt < 4; ++mt) acc[nt][mt] = (f32x4){0.f, 0.f, 0.f, 0.f};
#pragma unroll
    for (int kc = 0; kc < 4; ++kc) {
        int c0 = kc * 32;
        bf16x8 Ah[4], Al[4];
#pragma unroll
        for (int mt = 0; mt < 4; ++mt) {
            int base = (d0w + mt * 16 + tn) * 136 + c0 + 8 * q;
            Ah[mt] = *(const bf16x8*)&whi[base];
            Al[mt] = *(const bf16x8*)&wlo[base];
        }
#pragma unroll
        for (int nt = 0; nt < 4; ++nt) {
            const unsigned int* ph = (const unsigned int*)&xs_h[(nt * 16 + tn) * 130 + c0 + 8 * q];
            const unsigned int* pl = (const unsigned int*)&xs_l[(nt * 16 + tn) * 130 + c0 + 8 * q];
            union { bf16x8 v; unsigned int u[4]; } Bh, Bl;
            Bh.u[0] = ph[0]; Bh.u[1] = ph[1]; Bh.u[2] = ph[2]; Bh.u[3] = ph[3];
            Bl.u[0] = pl[0]; Bl.u[1] = pl[1]; Bl.u[2] = pl[2]; Bl.u[3] = pl[3];
#pragma unroll
            for (int mt = 0; mt < 4; ++mt) {
                acc[nt][mt] = __builtin_amdgcn_mfma_f32_16x16x32_bf16(Al[mt], Bh.v, acc[nt][mt], 0, 0, 0);
                acc[nt][mt] = __builtin_amdgcn_mfma_f32_16x16x32_bf16(Ah[mt], Bl.v, acc[nt][mt], 0, 0, 0);
                acc[nt][mt] = __builtin_amdgcn_mfma_f32_16x16x32_bf16(Ah[mt], Bh.v, acc[nt][mt], 0, 0, 0);
            }
        }
    }
#pragma unroll
    for (int nt = 0; nt < 4; ++nt) {
        float xl = xlasts[nt * 16 + tn];
        float s = 0.f, s2 = 0.f;
#pragma unroll
        for (int mt = 0; mt < 4; ++mt) {
#pragma unroll
            for (int r = 0; r < 4; ++r) {
                int d = d0w + mt * 16 + 4 * q + r;
                float v = acc[nt][mt][r] + biass[d] + w128s[d] * xl;
                acc[nt][mt][r] = v;
                s += v; s2 = fmaf(v, v, s2);
            }
        }
        ps[nt * 16 + tn][wave * 4 + q] = s;
        ps2[nt * 16 + tn][wave * 4 + q] = s2;
    }
    __syncthreads();
    if (tid < 64) {
        float s = 0.f, s2 = 0.f;
#pragma unroll
        for (int k = 0; k < 16; ++k) { s += ps[tid][k]; s2 += ps2[tid][k]; }
        float mean = s * (1.f / 256.f);
        float ex2 = s2 * (1.f / 256.f);
        mstat[tid] = mean;
        rstat[tid] = 1.f / sqrtf(ex2 - mean * mean + 1e-5f);
    }
    __syncthreads();
#pragma unroll
    for (int nt = 0; nt < 4; ++nt) {
        int tl = nt * 16 + tn;
        int t = t0 + tl;
        float mean = mstat[tl], rstd = rstat[tl];
        float ft = (float)t;
        float sq = 0.f;
#pragma unroll
        for (int mt = 0; mt < 4; ++mt) {
#pragma unroll
            for (int r = 0; r < 4; ++r) {
                int d = d0w + mt * 16 + 4 * q + r;
                float o = (acc[nt][mt][r] - mean) * rstd * gs[d] + bs[d];
                float freq = expf((float)(d & ~1) * (-9.210340371976184f / 256.f));
                float ang = ft * freq;
                o += (d & 1) ? cosf(ang) : sinf(ang);
                if (t < TT) h[((size_t)(b * DD + d)) * TT + t] = o;
                sq = fmaf(o, o, sq);
            }
        }
        ps[tl][wave * 4 + q] = sq;
    }
    __syncthreads();
    if (tid < 64) {
        int t = t0 + tid;
        if (t < TT) {
            float s = 0.f;
#pragma unroll
            for (int k = 0; k < 16; ++k) s += ps[tid][k];
            invn[b * TT + t] = 1.f / (sqrtf(s) + 1e-8f);
        }
    }
}

// ============ LayerNorm (in-place), single-pass ============
__global__ __launch_bounds__(256) void k_ln(const float* __restrict__ in, const float* __restrict__ g,
                                            const float* __restrict__ bia, float* __restrict__ out,
                                            float* __restrict__ invn) {
    int b = blockIdx.y, t0 = blockIdx.x * 64;
    int w = threadIdx.x >> 6, lane = threadIdx.x & 63;
    int t = t0 + lane;
    __shared__ float ps[4][64], ps2[4][64];
    float v[64];
    float s = 0.f, s2 = 0.f;
    bool ok = t < TT;
#pragma unroll
    for (int k = 0; k < 64; ++k) {
        float x = ok ? in[(size_t)(b * DD + (w + 4 * k)) * TT + t] : 0.f;
        v[k] = x;
        s += x; s2 = fmaf(x, x, s2);
    }
    ps[w][lane] = s; ps2[w][lane] = s2;
    __syncthreads();
    float mean = (ps[0][lane] + ps[1][lane] + ps[2][lane] + ps[3][lane]) * (1.f / 256.f);
    float ex2  = (ps2[0][lane] + ps2[1][lane] + ps2[2][lane] + ps2[3][lane]) * (1.f / 256.f);
    float rstd = 1.f / sqrtf(ex2 - mean * mean + 1e-5f);
    float sq = 0.f;
    if (ok) {
#pragma unroll
        for (int k = 0; k < 64; ++k) {
            int d = w + 4 * k;
            float o = (v[k] - mean) * rstd * g[d] + bia[d];
            out[(size_t)(b * DD + d) * TT + t] = o;
            sq = fmaf(o, o, sq);
        }
    }
    __syncthreads();
    ps[w][lane] = sq;
    __syncthreads();
    if (w == 0 && ok) {
        float tot = ps[0][lane] + ps[1][lane] + ps[2][lane] + ps[3][lane];
        invn[b * TT + t] = 1.f / (sqrtf(tot) + 1e-8f);
    }
}

__device__ __forceinline__ float gelu_exact(float y) {
    return 0.5f * y * (1.f + erff(y * 0.7071067811865476f));
}

// ============ MFMA conv, 32x32x16, one block per d, 32 batches ============
// Single accumulator per member (3 chained MFMAs: corrections then main) to stay
// within VGPR budget — R9's split aM/aC (64 acc VGPRs) spilled to scratch
// (VALUBusy 47%, +24MB HBM). 2 members share the wave-uniform Toeplitz B-frag.
// Snake balance: wave w does groups {w, 15-w}. D down to -16 covers the tile's
// upper triangle (zero-padded pk / staged zeros).
#define XS2 1032
__global__ __launch_bounds__(512) void k_conv32(float* __restrict__ h, const float* __restrict__ kk,
                                                const float* __restrict__ invn,
                                                const float* __restrict__ s4D, int layer) {
    __shared__ unsigned short Xh[32 * XS2], Xl[32 * XS2];
    __shared__ unsigned int pkh[1056], pkl[1056];
    int d = blockIdx.x;
    int tid = threadIdx.x;
    const float* krow = kk + (size_t)(layer * DD + d) * TT;
    for (int mm = tid; mm < 1056; mm += 512) {
        int m = mm - 32;
        float klo = (m >= 0 && m < TT) ? krow[m] : 0.f;
        float kpr = (m >= 1 && m <= TT) ? krow[m - 1] : 0.f;
        unsigned short lh = f2bf(klo); unsigned short ll = f2bf(klo - bf2f(lh));
        unsigned short ph = f2bf(kpr); unsigned short pl = f2bf(kpr - bf2f(ph));
        pkh[mm] = (unsigned int)lh | ((unsigned int)ph << 16);
        pkl[mm] = (unsigned int)ll | ((unsigned int)pl << 16);
    }
    for (int ii = tid; ii < 32 * 512; ii += 512) {
        int bb = ii >> 9;
        int tp = (ii & 511) * 2;
        const float* hrow = h + ((size_t)bb * DD + d) * TT;
        const float* ivr = invn + (size_t)bb * TT;
        float v0 = (tp < TT) ? hrow[tp] * ivr[tp] : 0.f;
        float v1 = (tp + 1 < TT) ? hrow[tp + 1] * ivr[tp + 1] : 0.f;
        unsigned short h0 = f2bf(v0), l0 = f2bf(v0 - bf2f(h0));
        unsigned short h1 = f2bf(v1), l1 = f2bf(v1 - bf2f(h1));
        ((unsigned int*)Xh)[(bb * XS2 + tp) >> 1] = (unsigned int)h0 | ((unsigned int)h1 << 16);
        ((unsigned int*)Xl)[(bb * XS2 + tp) >> 1] = (unsigned int)l0 | ((unsigned int)l1 << 16);
    }
    __syncthreads();
    float gate = 1.f / (1.f + expf(-s4D[layer * DD + d]));
    int wave = tid >> 6, lane = tid & 63;
    int nn = lane & 31, kq8 = (lane >> 5) << 3;
    for (int pass = 0; pass < 2; ++pass) {
        int G = pass ? (15 - wave) : wave;
        int jlo = 2 * G;
        f32x16 acc[2];
#pragma unroll
        for (int m = 0; m < 2; ++m)
#pragma unroll
            for (int r = 0; r < 16; ++r) acc[m][r] = 0.f;
        for (int D = 32 * jlo + 32; D >= -16; D -= 16) {
            int S32 = D + nn - kq8 + 32;
            union { bf16x8 v; unsigned int u[4]; } bh, bl;
            bh.u[0] = pkh[S32];     bl.u[0] = pkl[S32];
            bh.u[1] = pkh[S32 - 2]; bl.u[1] = pkl[S32 - 2];
            bh.u[2] = pkh[S32 - 4]; bl.u[2] = pkl[S32 - 4];
            bh.u[3] = pkh[S32 - 6]; bl.u[3] = pkl[S32 - 6];
#pragma unroll
            for (int m = 0; m < 2; ++m) {
                int u0 = (jlo + m) * 32 - D;
                if (u0 >= 0) {
                    const bf16x8 ah = *(const bf16x8*)&Xh[nn * XS2 + u0 + kq8];
                    const bf16x8 al = *(const bf16x8*)&Xl[nn * XS2 + u0 + kq8];
                    acc[m] = __builtin_amdgcn_mfma_f32_32x32x16_bf16(al, bh.v, acc[m], 0, 0, 0);
                    acc[m] = __builtin_amdgcn_mfma_f32_32x32x16_bf16(ah, bl.v, acc[m], 0, 0, 0);
                    acc[m] = __builtin_amdgcn_mfma_f32_32x32x16_bf16(ah, bh.v, acc[m], 0, 0, 0);
                }
            }
        }
#pragma unroll
        for (int m = 0; m < 2; ++m) {
            int t = (jlo + m) * 32 + nn;
            if (t < TT) {
#pragma unroll
                for (int r = 0; r < 16; ++r) {
                    int brow = (r & 3) + 8 * (r >> 2) + 4 * (lane >> 5);
                    size_t ix = ((size_t)brow * DD + d) * TT + t;
                    float y = acc[m][r];
                    float xn = bf2f(Xh[brow * XS2 + t]) + bf2f(Xl[brow * XS2 + t]);
                    float ho = xn * __builtin_amdgcn_rcpf(invn[brow * TT + t]);
                    h[ix] = gelu_exact(y + xn * gate) + 1.1f * ho;
                }
            }
        }
    }
}

// ============ MHA pooling ============
__global__ __launch_bounds__(256) void k_qprep(const float* __restrict__ cls, const float* __restrict__ inw,
                                               const float* __restrict__ inb, float* __restrict__ qk,
                                               float* __restrict__ qb) {
    __shared__ float Qv[256];
    int j = threadIdx.x;
    float a = inb[j];
    for (int i = 0; i < 256; ++i) a = fmaf(inw[j * DD + i], cls[i], a);
    Qv[j] = a;
    __syncthreads();
    const float scale = 0.17677669529663687f; // 1/sqrt(32)
    for (int idx = threadIdx.x; idx < 8 * 256; idx += 256) {
        int hh = idx >> 8, i = idx & 255;
        float s = 0.f;
        for (int jj = 0; jj < 32; ++jj)
            s = fmaf(Qv[hh * 32 + jj], inw[(DD + hh * 32 + jj) * DD + i], s);
        qk[idx] = s * scale;
    }
    if (threadIdx.x < 8) {
        int hh = threadIdx.x;
        float s = 0.f;
        for (int jj = 0; jj < 32; ++jj)
            s = fmaf(Qv[hh * 32 + jj], inb[DD + hh * 32 + jj], s);
        qb[hh] = s * scale;
    }
}

__global__ __launch_bounds__(256) void k_scores(const float* __restrict__ h, const float* __restrict__ cls,
                                                const float* __restrict__ qkw, const float* __restrict__ qbw,
                                                float* __restrict__ sc) {
    __shared__ float qks[8 * 256];
    int b = blockIdx.y;
    int s = blockIdx.x * 256 + threadIdx.x;
    for (int i = threadIdx.x; i < 2048; i += 256) qks[i] = qkw[i];
    __syncthreads();
    if (s >= TT + 1) return;
    float acc[8];
#pragma unroll
    for (int hh = 0; hh < 8; ++hh) acc[hh] = qbw[hh];
    if (s == 0) {
        for (int i = 0; i < 256; ++i) {
            float v = cls[i];
#pragma unroll
            for (int hh = 0; hh < 8; ++hh) acc[hh] = fmaf(qks[hh * 256 + i], v, acc[hh]);
        }
    } else {
        const float* hb = h + (size_t)b * DD * TT + (s - 1);
        for (int i = 0; i < 256; ++i) {
            float v = hb[(size_t)i * TT];
#pragma unroll
            for (int hh = 0; hh < 8; ++hh) acc[hh] = fmaf(qks[hh * 256 + i], v, acc[hh]);
        }
    }
#pragma unroll
    for (int hh = 0; hh < 8; ++hh) sc[(size_t)(b * 8 + hh) * 1024 + s] = acc[hh];
}

__global__ __launch_bounds__(256) void k_softmax(const float* __restrict__ sc, float* __restrict__ att) {
    int row = blockIdx.x;
    const float* p = sc + (size_t)row * 1024;
    float* o = att + (size_t)row * 1024;
    __shared__ float red[256];
    float m = -3.4e38f;
    for (int s = threadIdx.x; s < TT + 1; s += 256) m = fmaxf(m, p[s]);
    red[threadIdx.x] = m; __syncthreads();
    for (int st = 128; st; st >>= 1) {
        if (threadIdx.x < st) red[threadIdx.x] = fmaxf(red[threadIdx.x], red[threadIdx.x + st]);
        __syncthreads();
    }
    m = red[0]; __syncthreads();
    float sum = 0.f;
    for (int s = threadIdx.x; s < TT + 1; s += 256) {
        float e = expf(p[s] - m);
        o[s] = e; sum += e;
    }
    red[threadIdx.x] = sum; __syncthreads();
    for (int st = 128; st; st >>= 1) {
        if (threadIdx.x < st) red[threadIdx.x] += red[threadIdx.x + st];
        __syncthreads();
    }
    float inv = 1.f / red[0];
    for (int s = threadIdx.x; s < TT + 1; s += 256) o[s] *= inv;
}

__global__ __launch_bounds__(256) void k_ctx(const float* __restrict__ h, const float* __restrict__ cls,
                                             const float* __restrict__ att, float* __restrict__ ctx) {
    __shared__ float as[8][1024];
    int b = blockIdx.y, i0 = blockIdx.x * 32;
    for (int idx = threadIdx.x; idx < 8 * 1024; idx += 256) {
        int hh = idx >> 10, s = idx & 1023;
        as[hh][s] = (s < TT + 1) ? att[(size_t)(b * 8 + hh) * 1024 + s] : 0.f;
    }
    __syncthreads();
    int w = threadIdx.x >> 6, lane = threadIdx.x & 63;
    for (int ii = 0; ii < 8; ++ii) {
        int i = i0 + w * 8 + ii;
        const float* hb = h + (size_t)(b * DD + i) * TT;
        float acc[8];
#pragma unroll
        for (int hh = 0; hh < 8; ++hh) acc[hh] = 0.f;
        for (int t = lane; t < TT; t += 64) {
            float v = hb[t];
#pragma unroll
            for (int hh = 0; hh < 8; ++hh) acc[hh] = fmaf(as[hh][t + 1], v, acc[hh]);
        }
#pragma unroll
        for (int off = 32; off; off >>= 1)
#pragma unroll
            for (int hh = 0; hh < 8; ++hh) acc[hh] += __shfl_down(acc[hh], off);
        if (lane == 0) {
#pragma unroll
            for (int hh = 0; hh < 8; ++hh)
                ctx[(size_t)(b * 8 + hh) * DD + i] = acc[hh] + as[hh][0] * cls[i];
        }
    }
}

__global__ __launch_bounds__(256) void k_head(const float* __restrict__ ctx, const float* __restrict__ inw,
                                              const float* __restrict__ inb, const float* __restrict__ outw,
                                              const float* __restrict__ outb, const float* __restrict__ w1,
                                              const float* __restrict__ b1, const float* __restrict__ w2,
                                              const float* __restrict__ b2, float* __restrict__ out) {
    int b = blockIdx.x;
    __shared__ float cs[2048], ao[256], po[256], hid[128];
    for (int i = threadIdx.x; i < 2048; i += 256) cs[i] = ctx[(size_t)b * 2048 + i];
    __syncthreads();
    int j = threadIdx.x;
    {
        int hh = j >> 5;
        float a = inb[2 * DD + j];
        const float* wv = inw + (size_t)(2 * DD + j) * DD;
        for (int i = 0; i < 256; ++i) a = fmaf(wv[i], cs[hh * 256 + i], a);
        ao[j] = a;
    }
    __syncthreads();
    {
        float a = outb[j];
        for (int i = 0; i < 256; ++i) a = fmaf(outw[j * DD + i], ao[i], a);
        po[j] = a;
    }
    __syncthreads();
    if (j < 128) {
        float a = b1[j];
        for (int i = 0; i < 256; ++i) a = fmaf(w1[j * 256 + i], po[i], a);
        hid[j] = fmaxf(a, 0.f);
    }
    __syncthreads();
    if (j == 0) {
        float a = b2[0];
        for (int i = 0; i < 128; ++i) a = fmaf(w2[i], hid[i], a);
        out[b] = a;
    }
}

extern "C" void kernel_launch(void* const* d_in, const int* in_sizes, int n_in,
                              void* d_out, int out_size, void* d_ws, size_t ws_size,
                              hipStream_t stream) {
    (void)in_sizes; (void)n_in; (void)out_size; (void)ws_size;
    const float* x        = (const float*)d_in[0];
    const float* w_in     = (const float*)d_in[1];
    const float* b_in     = (const float*)d_in[2];
    const float* ln_in_g  = (const float*)d_in[3];
    const float* ln_in_b  = (const float*)d_in[4];
    const float* s4B      = (const float*)d_in[5];
    const float* s4C      = (const float*)d_in[6];
    const float* s4logdt  = (const float*)d_in[7];
    const float* s4D      = (const float*)d_in[8];
    const float* ln_g     = (const float*)d_in[9];
    const float* ln_b     = (const float*)d_in[10];
    const float* cls      = (const float*)d_in[11];
    const float* mha_in_w = (const float*)d_in[12];
    const float* mha_in_b = (const float*)d_in[13];
    const float* mha_out_w= (const float*)d_in[14];
    const float* mha_out_b= (const float*)d_in[15];
    const float* head_w1  = (const float*)d_in[16];
    const float* head_b1  = (const float*)d_in[17];
    const float* head_w2  = (const float*)d_in[18];
    const float* head_b2  = (const float*)d_in[19];

    float* ws   = (float*)d_ws;
    float* h    = ws + OFF_H;
    float* kker = ws + OFF_K;
    float* invn = ws + OFF_INV;
    float* P  = h;                 // 33 * 4096
    float* Q  = h + 540672;        // 32 * 4096
    float* Lb = h + 1064960;
    float* Rb = h + 3162112;
    float* qkb  = ws + OFF_MHA;
    float* qbb  = qkb + 2048;
    float* scb  = qbb + 16;
    float* attb = scb + 262144;
    float* ctxb = attb + 262144;
    unsigned short* whi = (unsigned short*)scb;
    unsigned short* wlo = whi + 256 * 136;

    k_build_ad<<<dim3(65), dim3(1024), 0, stream>>>(s4logdt, P, w_in, whi, wlo);
    for (int m = 1; m <= 5; ++m) {
        int half = 1 << (m - 1);
        k_mm64<<<dim3(half), dim3(256), 0, stream>>>(P, half, (m == 5) ? Q : nullptr);
    }
    for (int m = 1; m <= 5; ++m) {
        int half = 1 << (m - 1);
        int cnt = (m == 5) ? 15 : half;
        k_mm64<<<dim3(cnt), dim3(256), 0, stream>>>(Q, half, nullptr);
    }
    k_lr<<<dim3(NLY * 64), dim3(256), 0, stream>>>(P, Q, s4B, s4C, Lb, Rb);
    k_kker<<<dim3(NLY * 256), dim3(256), 0, stream>>>(Lb, Rb, kker);

    k_embed_mfma<<<dim3(16, BB), dim3(256), 0, stream>>>(x, whi, wlo, w_in, b_in,
                                                         ln_in_g, ln_in_b, h, invn);

    for (int l = 0; l < NLY; ++l) {
        k_conv32<<<dim3(DD), dim3(512), 0, stream>>>(h, kker, invn, s4D, l);
        k_ln<<<dim3(16, BB), dim3(256), 0, stream>>>(h, ln_g + l * DD, ln_b + l * DD, h, invn);
    }

    k_qprep<<<dim3(1), dim3(256), 0, stream>>>(cls, mha_in_w, mha_in_b, qkb, qbb);
    k_scores<<<dim3(4, BB), dim3(256), 0, stream>>>(h, cls, qkb, qbb, scb);
    k_softmax<<<dim3(256), dim3(256), 0, stream>>>(scb, attb);
    k_ctx<<<dim3(8, BB), dim3(256), 0, stream>>>(h, cls, attb, ctxb);
    k_head<<<dim3(BB), dim3(256), 0, stream>>>(ctxb, mha_in_w, mha_in_b, mha_out_w, mha_out_b,
                                               head_w1, head_b1, head_w2, head_b2, (float*)d_out);
}

// Round 12
// 655.248 us; speedup vs baseline: 1.2000x; 1.0361x over previous
//
#include <hip/hip_runtime.h>

#define BB 32
#define CC 129
#define TT 1000
#define DD 256
#define NN 64
#define NLY 4

// ---------------- workspace layout (floats) ----------------
#define OFF_H    0
#define OFF_K    8192000
#define OFF_INV  9232384
#define OFF_MHA  9264384

typedef __attribute__((ext_vector_type(8))) short bf16x8;
typedef __attribute__((ext_vector_type(4))) float f32x4;
typedef __attribute__((ext_vector_type(16))) float f32x16;

__device__ __forceinline__ unsigned short f2bf(float x) {
    unsigned int u = __float_as_uint(x);
    unsigned int r = (u + 0x7FFF + ((u >> 16) & 1)) >> 16;
    return (unsigned short)r;
}
__device__ __forceinline__ float bf2f(unsigned short b) {
    return __uint_as_float(((unsigned int)b) << 16);
}

// ============ Ad build (block 0) + w_in split-bf16 prep (blocks 1..64) ============
#define ST 131
__global__ __launch_bounds__(1024) void k_build_ad(const float* __restrict__ logdt,
                                                   float* __restrict__ P,
                                                   const float* __restrict__ w_in,
                                                   unsigned short* __restrict__ whi,
                                                   unsigned short* __restrict__ wlo) {
    __shared__ float M[64 * ST + 16];
    int tid = threadIdx.x;
    if (blockIdx.x != 0) {
        int d = (blockIdx.x - 1) * 4 + (tid >> 8);
        int c = tid & 255;
        if (c < 136) {
            float v = (c < CC) ? w_in[d * CC + c] : 0.f;
            unsigned short h = f2bf(v);
            whi[d * 136 + c] = h;
            wlo[d * 136 + c] = f2bf(v - bf2f(h));
        }
        return;
    }
    int q = tid >> 6, r = tid & 63;
    float dt = expf(logdt[0]);
    dt = fminf(fmaxf(dt, 1e-4f), 0.1f);
    float hh = dt * 0.5f;
    float Pr = sqrtf(1.f + 2.f * (float)r);
    for (int j = q; j < 130; j += 16) {
        if (j < 64) {
            float a;
            if (r == j) a = -((float)r + 0.5f);
            else { float m = Pr * sqrtf(1.f + 2.f * (float)j); a = (r > j) ? -m : m; }
            M[r * ST + j] = ((r == j) ? 1.f : 0.f) - hh * a;
        } else {
            M[r * ST + j] = (r == (j - 64)) ? 2.f : 0.f;
        }
    }
    __syncthreads();
    for (int c = 0; c < 64; ++c) {
        float invp = 1.f / M[c * ST + c];
        float f = M[r * ST + c] * invp;
        if (r != c) {
            int j0 = (c + 1) + ((q - (c + 1)) & 15);
            const float* prow = &M[c * ST];
            float* mrow = &M[r * ST];
            for (int j = j0; j < 130; j += 16)
                mrow[j] = fmaf(-f, prow[j], mrow[j]);
        }
        __syncthreads();
    }
    float invd = 1.f / M[r * ST + r];
    for (int j = q; j < 64; j += 16) {
        P[r * 64 + j] = (r == j) ? 1.f : 0.f;
        P[4096 + r * 64 + j] = M[r * ST + 64 + j] * invd - ((r == j) ? 1.f : 0.f);
    }
}

// ============ power-tree matmul; optional Q0/Q1 fold-in on the j==32 block ============
__global__ __launch_bounds__(256) void k_mm64(float* __restrict__ base, int half,
                                              float* __restrict__ qdst) {
    __shared__ float As[4096], Bs[4096];
    int j = half + 1 + blockIdx.x;
    const float* Am = base + (size_t)half * 4096;
    const float* Bm = base + (size_t)(j - half) * 4096;
    float* Dm = base + (size_t)j * 4096;
    for (int i = threadIdx.x; i < 4096; i += 256) { As[i] = Am[i]; Bs[i] = Bm[i]; }
    __syncthreads();
    int tr = (threadIdx.x >> 4) << 2;
    int tc = (threadIdx.x & 15) << 2;
    float acc[4][4];
#pragma unroll
    for (int u = 0; u < 4; ++u)
#pragma unroll
        for (int v = 0; v < 4; ++v) acc[u][v] = 0.f;
    for (int k = 0; k < 64; ++k) {
        float a0 = As[(tr + 0) * 64 + k], a1 = As[(tr + 1) * 64 + k];
        float a2 = As[(tr + 2) * 64 + k], a3 = As[(tr + 3) * 64 + k];
        float b0 = Bs[k * 64 + tc + 0], b1 = Bs[k * 64 + tc + 1];
        float b2 = Bs[k * 64 + tc + 2], b3 = Bs[k * 64 + tc + 3];
        acc[0][0] = fmaf(a0, b0, acc[0][0]); acc[0][1] = fmaf(a0, b1, acc[0][1]);
        acc[0][2] = fmaf(a0, b2, acc[0][2]); acc[0][3] = fmaf(a0, b3, acc[0][3]);
        acc[1][0] = fmaf(a1, b0, acc[1][0]); acc[1][1] = fmaf(a1, b1, acc[1][1]);
        acc[1][2] = fmaf(a1, b2, acc[1][2]); acc[1][3] = fmaf(a1, b3, acc[1][3]);
        acc[2][0] = fmaf(a2, b0, acc[2][0]); acc[2][1] = fmaf(a2, b1, acc[2][1]);
        acc[2][2] = fmaf(a2, b2, acc[2][2]); acc[2][3] = fmaf(a2, b3, acc[2][3]);
        acc[3][0] = fmaf(a3, b0, acc[3][0]); acc[3][1] = fmaf(a3, b1, acc[3][1]);
        acc[3][2] = fmaf(a3, b2, acc[3][2]); acc[3][3] = fmaf(a3, b3, acc[3][3]);
    }
#pragma unroll
    for (int u = 0; u < 4; ++u)
#pragma unroll
        for (int v = 0; v < 4; ++v) Dm[(tr + u) * 64 + tc + v] = acc[u][v];
    if (qdst && j == 32) {
#pragma unroll
        for (int u = 0; u < 4; ++u)
#pragma unroll
            for (int v = 0; v < 4; ++v) {
                int rr = tr + u, cc = tc + v;
                qdst[rr * 64 + cc] = (rr == cc) ? 1.f : 0.f;
                qdst[4096 + rr * 64 + cc] = acc[u][v];
            }
    }
}

// ============ L / R ============
__global__ __launch_bounds__(256) void k_lr(const float* __restrict__ P, const float* __restrict__ Q,
                                            const float* __restrict__ s4B, const float* __restrict__ s4C,
                                            float* __restrict__ L, float* __restrict__ R) {
    __shared__ float Ms[4096];
    int l = blockIdx.x >> 6, rem = blockIdx.x & 63, which = rem >> 5, idx = rem & 31;
    const float* M = which ? (P + (size_t)idx * 4096)
                           : (Q + (size_t)idx * 4096);
    for (int i = threadIdx.x; i < 4096; i += 256) Ms[i] = M[i];
    __syncthreads();
    int d = threadIdx.x;
    if (which == 0) {
        float* dst = L + (((size_t)(l * DD + d) * 32 + idx) * 64);
        for (int jc = 0; jc < 8; ++jc) {
            float acc[8];
#pragma unroll
            for (int u = 0; u < 8; ++u) acc[u] = 0.f;
            for (int i = 0; i < 64; ++i) {
                float bv = s4B[(l * NN + i) * DD + d];
#pragma unroll
                for (int u = 0; u < 8; ++u)
                    acc[u] = fmaf(bv, Ms[i * 64 + jc * 8 + u], acc[u]);
            }
#pragma unroll
            for (int u = 0; u < 8; ++u) dst[jc * 8 + u] = acc[u];
        }
    } else {
        float* dst = R + (((size_t)(l * DD + d) * 32 + idx) * 64);
        const float* Cp = s4C + (size_t)(l * DD + d) * NN;
        for (int ic = 0; ic < 8; ++ic) {
            float acc[8];
#pragma unroll
            for (int u = 0; u < 8; ++u) acc[u] = 0.f;
            for (int j = 0; j < 64; ++j) {
                float cv = Cp[j];
#pragma unroll
                for (int u = 0; u < 8; ++u)
                    acc[u] = fmaf(Ms[(ic * 8 + u) * 64 + j], cv, acc[u]);
            }
#pragma unroll
            for (int u = 0; u < 8; ++u) dst[ic * 8 + u] = acc[u];
        }
    }
}

// ============ kernel assembly ============
__global__ __launch_bounds__(256) void k_kker(const float* __restrict__ L, const float* __restrict__ R,
                                              float* __restrict__ kk) {
    __shared__ float Ls[32 * 65], Rs[32 * 65];
    int l = blockIdx.x >> 8, d = blockIdx.x & 255;
    const float* Lp = L + ((size_t)(l * DD + d) * 32) * 64;
    const float* Rp = R + ((size_t)(l * DD + d) * 32) * 64;
    for (int i = threadIdx.x; i < 2048; i += 256) {
        int row = i >> 6, col = i & 63;
        Ls[row * 65 + col] = Lp[i];
        Rs[row * 65 + col] = Rp[i];
    }
    __syncthreads();
    for (int t = threadIdx.x; t < TT; t += 256) {
        int kq = t >> 5, r = t & 31;
        const float* lr = &Ls[kq * 65];
        const float* rr = &Rs[r * 65];
        float a = 0.f;
#pragma unroll 8
        for (int m = 0; m < 64; ++m) a = fmaf(lr[m], rr[m], a);
        kk[(size_t)(l * DD + d) * TT + t] = a * expf(-0.01f * (float)t);
    }
}

// ============ MFMA embed + fused LayerNorm + pos-encoding + invn ============
__global__ __launch_bounds__(256) void k_embed_mfma(const float* __restrict__ x,
                                                    const unsigned short* __restrict__ whi,
                                                    const unsigned short* __restrict__ wlo,
                                                    const float* __restrict__ w_in,
                                                    const float* __restrict__ b_in,
                                                    const float* __restrict__ lng,
                                                    const float* __restrict__ lnb,
                                                    float* __restrict__ h,
                                                    float* __restrict__ invn) {
    __shared__ unsigned short xs_h[64 * 130], xs_l[64 * 130];
    __shared__ float xlasts[64], w128s[256], biass[256], gs[256], bs[256];
    __shared__ float ps[64][16], ps2[64][16];
    __shared__ float mstat[64], rstat[64];
    int b = blockIdx.y, t0 = blockIdx.x * 64;
    int tid = threadIdx.x;
    for (int i = tid; i < CC * 64; i += 256) {
        int c = i >> 6, tl = i & 63;
        int t = t0 + tl;
        float v = (t < TT) ? x[(size_t)(b * CC + c) * TT + t] : 0.f;
        if (c == 128) {
            xlasts[tl] = v;
        } else {
            unsigned short hh = f2bf(v);
            xs_h[tl * 130 + c] = hh;
            xs_l[tl * 130 + c] = f2bf(v - bf2f(hh));
        }
    }
    w128s[tid] = w_in[tid * CC + 128];
    biass[tid] = b_in[tid];
    gs[tid] = lng[tid];
    bs[tid] = lnb[tid];
    __syncthreads();
    int wave = tid >> 6, lane = tid & 63;
    int tn = lane & 15, q = lane >> 4;
    int d0w = wave * 64;
    f32x4 acc[4][4];
#pragma unroll
    for (int nt = 0; nt < 4; ++nt)
#pragma unroll
        for (int mt = 0; mt < 4; ++mt) acc[nt][mt] = (f32x4){0.f, 0.f, 0.f, 0.f};
#pragma unroll
    for (int kc = 0; kc < 4; ++kc) {
        int c0 = kc * 32;
        bf16x8 Ah[4], Al[4];
#pragma unroll
        for (int mt = 0; mt < 4; ++mt) {
            int base = (d0w + mt * 16 + tn) * 136 + c0 + 8 * q;
            Ah[mt] = *(const bf16x8*)&whi[base];
            Al[mt] = *(const bf16x8*)&wlo[base];
        }
#pragma unroll
        for (int nt = 0; nt < 4; ++nt) {
            const unsigned int* ph = (const unsigned int*)&xs_h[(nt * 16 + tn) * 130 + c0 + 8 * q];
            const unsigned int* pl = (const unsigned int*)&xs_l[(nt * 16 + tn) * 130 + c0 + 8 * q];
            union { bf16x8 v; unsigned int u[4]; } Bh, Bl;
            Bh.u[0] = ph[0]; Bh.u[1] = ph[1]; Bh.u[2] = ph[2]; Bh.u[3] = ph[3];
            Bl.u[0] = pl[0]; Bl.u[1] = pl[1]; Bl.u[2] = pl[2]; Bl.u[3] = pl[3];
#pragma unroll
            for (int mt = 0; mt < 4; ++mt) {
                acc[nt][mt] = __builtin_amdgcn_mfma_f32_16x16x32_bf16(Al[mt], Bh.v, acc[nt][mt], 0, 0, 0);
                acc[nt][mt] = __builtin_amdgcn_mfma_f32_16x16x32_bf16(Ah[mt], Bl.v, acc[nt][mt], 0, 0, 0);
                acc[nt][mt] = __builtin_amdgcn_mfma_f32_16x16x32_bf16(Ah[mt], Bh.v, acc[nt][mt], 0, 0, 0);
            }
        }
    }
#pragma unroll
    for (int nt = 0; nt < 4; ++nt) {
        float xl = xlasts[nt * 16 + tn];
        float s = 0.f, s2 = 0.f;
#pragma unroll
        for (int mt = 0; mt < 4; ++mt) {
#pragma unroll
            for (int r = 0; r < 4; ++r) {
                int d = d0w + mt * 16 + 4 * q + r;
                float v = acc[nt][mt][r] + biass[d] + w128s[d] * xl;
                acc[nt][mt][r] = v;
                s += v; s2 = fmaf(v, v, s2);
            }
        }
        ps[nt * 16 + tn][wave * 4 + q] = s;
        ps2[nt * 16 + tn][wave * 4 + q] = s2;
    }
    __syncthreads();
    if (tid < 64) {
        float s = 0.f, s2 = 0.f;
#pragma unroll
        for (int k = 0; k < 16; ++k) { s += ps[tid][k]; s2 += ps2[tid][k]; }
        float mean = s * (1.f / 256.f);
        float ex2 = s2 * (1.f / 256.f);
        mstat[tid] = mean;
        rstat[tid] = 1.f / sqrtf(ex2 - mean * mean + 1e-5f);
    }
    __syncthreads();
#pragma unroll
    for (int nt = 0; nt < 4; ++nt) {
        int tl = nt * 16 + tn;
        int t = t0 + tl;
        float mean = mstat[tl], rstd = rstat[tl];
        float ft = (float)t;
        float sq = 0.f;
#pragma unroll
        for (int mt = 0; mt < 4; ++mt) {
#pragma unroll
            for (int r = 0; r < 4; ++r) {
                int d = d0w + mt * 16 + 4 * q + r;
                float o = (acc[nt][mt][r] - mean) * rstd * gs[d] + bs[d];
                float freq = expf((float)(d & ~1) * (-9.210340371976184f / 256.f));
                float ang = ft * freq;
                o += (d & 1) ? cosf(ang) : sinf(ang);
                if (t < TT) h[((size_t)(b * DD + d)) * TT + t] = o;
                sq = fmaf(o, o, sq);
            }
        }
        ps[tl][wave * 4 + q] = sq;
    }
    __syncthreads();
    if (tid < 64) {
        int t = t0 + tid;
        if (t < TT) {
            float s = 0.f;
#pragma unroll
            for (int k = 0; k < 16; ++k) s += ps[tid][k];
            invn[b * TT + t] = 1.f / (sqrtf(s) + 1e-8f);
        }
    }
}

// ============ LayerNorm (in-place), single-pass ============
__global__ __launch_bounds__(256) void k_ln(const float* __restrict__ in, const float* __restrict__ g,
                                            const float* __restrict__ bia, float* __restrict__ out,
                                            float* __restrict__ invn) {
    int b = blockIdx.y, t0 = blockIdx.x * 64;
    int w = threadIdx.x >> 6, lane = threadIdx.x & 63;
    int t = t0 + lane;
    __shared__ float ps[4][64], ps2[4][64];
    float v[64];
    float s = 0.f, s2 = 0.f;
    bool ok = t < TT;
#pragma unroll
    for (int k = 0; k < 64; ++k) {
        float x = ok ? in[(size_t)(b * DD + (w + 4 * k)) * TT + t] : 0.f;
        v[k] = x;
        s += x; s2 = fmaf(x, x, s2);
    }
    ps[w][lane] = s; ps2[w][lane] = s2;
    __syncthreads();
    float mean = (ps[0][lane] + ps[1][lane] + ps[2][lane] + ps[3][lane]) * (1.f / 256.f);
    float ex2  = (ps2[0][lane] + ps2[1][lane] + ps2[2][lane] + ps2[3][lane]) * (1.f / 256.f);
    float rstd = 1.f / sqrtf(ex2 - mean * mean + 1e-5f);
    float sq = 0.f;
    if (ok) {
#pragma unroll
        for (int k = 0; k < 64; ++k) {
            int d = w + 4 * k;
            float o = (v[k] - mean) * rstd * g[d] + bia[d];
            out[(size_t)(b * DD + d) * TT + t] = o;
            sq = fmaf(o, o, sq);
        }
    }
    __syncthreads();
    ps[w][lane] = sq;
    __syncthreads();
    if (w == 0 && ok) {
        float tot = ps[0][lane] + ps[1][lane] + ps[2][lane] + ps[3][lane];
        invn[b * TT + t] = 1.f / (sqrtf(tot) + 1e-8f);
    }
}

__device__ __forceinline__ float gelu_exact(float y) {
    return 0.5f * y * (1.f + erff(y * 0.7071067811865476f));
}

// ============ MFMA conv, 32x32x16, one block per d, 32 batches ============
#define XS2 1032
__global__ __launch_bounds__(512) void k_conv32(float* __restrict__ h, const float* __restrict__ kk,
                                                const float* __restrict__ invn,
                                                const float* __restrict__ s4D, int layer) {
    __shared__ unsigned short Xh[32 * XS2], Xl[32 * XS2];
    __shared__ unsigned int pkh[1056], pkl[1056];
    int d = blockIdx.x;
    int tid = threadIdx.x;
    const float* krow = kk + (size_t)(layer * DD + d) * TT;
    for (int mm = tid; mm < 1056; mm += 512) {
        int m = mm - 32;
        float klo = (m >= 0 && m < TT) ? krow[m] : 0.f;
        float kpr = (m >= 1 && m <= TT) ? krow[m - 1] : 0.f;
        unsigned short lh = f2bf(klo); unsigned short ll = f2bf(klo - bf2f(lh));
        unsigned short ph = f2bf(kpr); unsigned short pl = f2bf(kpr - bf2f(ph));
        pkh[mm] = (unsigned int)lh | ((unsigned int)ph << 16);
        pkl[mm] = (unsigned int)ll | ((unsigned int)pl << 16);
    }
    for (int ii = tid; ii < 32 * 512; ii += 512) {
        int bb = ii >> 9;
        int tp = (ii & 511) * 2;
        const float* hrow = h + ((size_t)bb * DD + d) * TT;
        const float* ivr = invn + (size_t)bb * TT;
        float v0 = (tp < TT) ? hrow[tp] * ivr[tp] : 0.f;
        float v1 = (tp + 1 < TT) ? hrow[tp + 1] * ivr[tp + 1] : 0.f;
        unsigned short h0 = f2bf(v0), l0 = f2bf(v0 - bf2f(h0));
        unsigned short h1 = f2bf(v1), l1 = f2bf(v1 - bf2f(h1));
        ((unsigned int*)Xh)[(bb * XS2 + tp) >> 1] = (unsigned int)h0 | ((unsigned int)h1 << 16);
        ((unsigned int*)Xl)[(bb * XS2 + tp) >> 1] = (unsigned int)l0 | ((unsigned int)l1 << 16);
    }
    __syncthreads();
    float gate = 1.f / (1.f + expf(-s4D[layer * DD + d]));
    int wave = tid >> 6, lane = tid & 63;
    int nn = lane & 31, kq8 = (lane >> 5) << 3;
    for (int pass = 0; pass < 2; ++pass) {
        int G = pass ? (15 - wave) : wave;
        int jlo = 2 * G;
        f32x16 acc[2];
#pragma unroll
        for (int m = 0; m < 2; ++m)
#pragma unroll
            for (int r = 0; r < 16; ++r) acc[m][r] = 0.f;
        for (int D = 32 * jlo + 32; D >= -16; D -= 16) {
            int S32 = D + nn - kq8 + 32;
            union { bf16x8 v; unsigned int u[4]; } bh, bl;
            bh.u[0] = pkh[S32];     bl.u[0] = pkl[S32];
            bh.u[1] = pkh[S32 - 2]; bl.u[1] = pkl[S32 - 2];
            bh.u[2] = pkh[S32 - 4]; bl.u[2] = pkl[S32 - 4];
            bh.u[3] = pkh[S32 - 6]; bl.u[3] = pkl[S32 - 6];
#pragma unroll
            for (int m = 0; m < 2; ++m) {
                int u0 = (jlo + m) * 32 - D;
                if (u0 >= 0) {
                    const bf16x8 ah = *(const bf16x8*)&Xh[nn * XS2 + u0 + kq8];
                    const bf16x8 al = *(const bf16x8*)&Xl[nn * XS2 + u0 + kq8];
                    acc[m] = __builtin_amdgcn_mfma_f32_32x32x16_bf16(al, bh.v, acc[m], 0, 0, 0);
                    acc[m] = __builtin_amdgcn_mfma_f32_32x32x16_bf16(ah, bl.v, acc[m], 0, 0, 0);
                    acc[m] = __builtin_amdgcn_mfma_f32_32x32x16_bf16(ah, bh.v, acc[m], 0, 0, 0);
                }
            }
        }
#pragma unroll
        for (int m = 0; m < 2; ++m) {
            int t = (jlo + m) * 32 + nn;
            if (t < TT) {
#pragma unroll
                for (int r = 0; r < 16; ++r) {
                    int brow = (r & 3) + 8 * (r >> 2) + 4 * (lane >> 5);
                    size_t ix = ((size_t)brow * DD + d) * TT + t;
                    float y = acc[m][r];
                    float xn = bf2f(Xh[brow * XS2 + t]) + bf2f(Xl[brow * XS2 + t]);
                    float ho = xn * __builtin_amdgcn_rcpf(invn[brow * TT + t]);
                    h[ix] = gelu_exact(y + xn * gate) + 1.1f * ho;
                }
            }
        }
    }
}

// ============ MHA pooling ============
__global__ __launch_bounds__(256) void k_qprep(const float* __restrict__ cls, const float* __restrict__ inw,
                                               const float* __restrict__ inb, float* __restrict__ qk,
                                               float* __restrict__ qb) {
    __shared__ float Qv[256];
    int j = threadIdx.x;
    float a = inb[j];
    for (int i = 0; i < 256; ++i) a = fmaf(inw[j * DD + i], cls[i], a);
    Qv[j] = a;
    __syncthreads();
    const float scale = 0.17677669529663687f; // 1/sqrt(32)
    for (int idx = threadIdx.x; idx < 8 * 256; idx += 256) {
        int hh = idx >> 8, i = idx & 255;
        float s = 0.f;
        for (int jj = 0; jj < 32; ++jj)
            s = fmaf(Qv[hh * 32 + jj], inw[(DD + hh * 32 + jj) * DD + i], s);
        qk[idx] = s * scale;
    }
    if (threadIdx.x < 8) {
        int hh = threadIdx.x;
        float s = 0.f;
        for (int jj = 0; jj < 32; ++jj)
            s = fmaf(Qv[hh * 32 + jj], inb[DD + hh * 32 + jj], s);
        qb[hh] = s * scale;
    }
}

// 128 threads, grid (8, B): 1 block/CU-ish for latency hiding
__global__ __launch_bounds__(128) void k_scores(const float* __restrict__ h, const float* __restrict__ cls,
                                                const float* __restrict__ qkw, const float* __restrict__ qbw,
                                                float* __restrict__ sc) {
    __shared__ float qks[8 * 256];
    int b = blockIdx.y;
    int s = blockIdx.x * 128 + threadIdx.x;
    for (int i = threadIdx.x; i < 2048; i += 128) qks[i] = qkw[i];
    __syncthreads();
    if (s >= TT + 1) return;
    float acc[8];
#pragma unroll
    for (int hh = 0; hh < 8; ++hh) acc[hh] = qbw[hh];
    if (s == 0) {
        for (int i = 0; i < 256; ++i) {
            float v = cls[i];
#pragma unroll
            for (int hh = 0; hh < 8; ++hh) acc[hh] = fmaf(qks[hh * 256 + i], v, acc[hh]);
        }
    } else {
        const float* hb = h + (size_t)b * DD * TT + (s - 1);
        for (int i = 0; i < 256; ++i) {
            float v = hb[(size_t)i * TT];
#pragma unroll
            for (int hh = 0; hh < 8; ++hh) acc[hh] = fmaf(qks[hh * 256 + i], v, acc[hh]);
        }
    }
#pragma unroll
    for (int hh = 0; hh < 8; ++hh) sc[(size_t)(b * 8 + hh) * 1024 + s] = acc[hh];
}

__global__ __launch_bounds__(256) void k_softmax(const float* __restrict__ sc, float* __restrict__ att) {
    int row = blockIdx.x;
    const float* p = sc + (size_t)row * 1024;
    float* o = att + (size_t)row * 1024;
    __shared__ float red[256];
    float m = -3.4e38f;
    for (int s = threadIdx.x; s < TT + 1; s += 256) m = fmaxf(m, p[s]);
    red[threadIdx.x] = m; __syncthreads();
    for (int st = 128; st; st >>= 1) {
        if (threadIdx.x < st) red[threadIdx.x] = fmaxf(red[threadIdx.x], red[threadIdx.x + st]);
        __syncthreads();
    }
    m = red[0]; __syncthreads();
    float sum = 0.f;
    for (int s = threadIdx.x; s < TT + 1; s += 256) {
        float e = expf(p[s] - m);
        o[s] = e; sum += e;
    }
    red[threadIdx.x] = sum; __syncthreads();
    for (int st = 128; st; st >>= 1) {
        if (threadIdx.x < st) red[threadIdx.x] += red[threadIdx.x + st];
        __syncthreads();
    }
    float inv = 1.f / red[0];
    for (int s = threadIdx.x; s < TT + 1; s += 256) o[s] *= inv;
}

// ============ ctx stage 1: t-chunked partials ============
// grid (8 igroups, 4 tchunks, B). partial[tc][b][hh][i] = sum_{u<250} att[b,hh,tc*250+1+u] * h[b,i,tc*250+u]
__global__ __launch_bounds__(256) void k_ctx1(const float* __restrict__ h,
                                              const float* __restrict__ att,
                                              float* __restrict__ ctx1) {
    __shared__ float as[8][256];
    int i0 = blockIdx.x * 32, tc = blockIdx.y, b = blockIdx.z;
    int tid = threadIdx.x;
    int sbase = tc * 250 + 1;
    for (int idx = tid; idx < 2048; idx += 256) {
        int hh = idx >> 8, u = idx & 255;
        as[hh][u] = (u < 250) ? att[(size_t)(b * 8 + hh) * 1024 + sbase + u] : 0.f;
    }
    __syncthreads();
    int w = tid >> 6, lane = tid & 63;
    for (int ii = 0; ii < 8; ++ii) {
        int i = i0 + w * 8 + ii;
        const float* hb = h + ((size_t)(b * DD + i)) * TT + tc * 250;
        float acc[8];
#pragma unroll
        for (int hh = 0; hh < 8; ++hh) acc[hh] = 0.f;
        for (int u = lane; u < 250; u += 64) {
            float v = hb[u];
#pragma unroll
            for (int hh = 0; hh < 8; ++hh) acc[hh] = fmaf(as[hh][u], v, acc[hh]);
        }
#pragma unroll
        for (int off = 32; off; off >>= 1)
#pragma unroll
            for (int hh = 0; hh < 8; ++hh) acc[hh] += __shfl_down(acc[hh], off);
        if (lane == 0) {
#pragma unroll
            for (int hh = 0; hh < 8; ++hh)
                ctx1[(((size_t)tc * BB + b) * 8 + hh) * DD + i] = acc[hh];
        }
    }
}

// ============ head: reduce ctx partials + cls term, then MLP ============
__global__ __launch_bounds__(256) void k_head(const float* __restrict__ ctx1,
                                              const float* __restrict__ att,
                                              const float* __restrict__ cls,
                                              const float* __restrict__ inw,
                                              const float* __restrict__ inb, const float* __restrict__ outw,
                                              const float* __restrict__ outb, const float* __restrict__ w1,
                                              const float* __restrict__ b1, const float* __restrict__ w2,
                                              const float* __restrict__ b2, float* __restrict__ out) {
    int b = blockIdx.x;
    __shared__ float cs[2048], ao[256], po[256], hid[128];
    int j = threadIdx.x;
    {
        float cv = cls[j];
#pragma unroll
        for (int hh = 0; hh < 8; ++hh) {
            float a = att[(size_t)(b * 8 + hh) * 1024] * cv;
#pragma unroll
            for (int tc = 0; tc < 4; ++tc)
                a += ctx1[(((size_t)tc * BB + b) * 8 + hh) * DD + j];
            cs[hh * 256 + j] = a;
        }
    }
    __syncthreads();
    {
        int hh = j >> 5;
        float a = inb[2 * DD + j];
        const float* wv = inw + (size_t)(2 * DD + j) * DD;
        for (int i = 0; i < 256; ++i) a = fmaf(wv[i], cs[hh * 256 + i], a);
        ao[j] = a;
    }
    __syncthreads();
    {
        float a = outb[j];
        for (int i = 0; i < 256; ++i) a = fmaf(outw[j * DD + i], ao[i], a);
        po[j] = a;
    }
    __syncthreads();
    if (j < 128) {
        float a = b1[j];
        for (int i = 0; i < 256; ++i) a = fmaf(w1[j * 256 + i], po[i], a);
        hid[j] = fmaxf(a, 0.f);
    }
    __syncthreads();
    if (j == 0) {
        float a = b2[0];
        for (int i = 0; i < 128; ++i) a = fmaf(w2[i], hid[i], a);
        out[b] = a;
    }
}

extern "C" void kernel_launch(void* const* d_in, const int* in_sizes, int n_in,
                              void* d_out, int out_size, void* d_ws, size_t ws_size,
                              hipStream_t stream) {
    (void)in_sizes; (void)n_in; (void)out_size; (void)ws_size;
    const float* x        = (const float*)d_in[0];
    const float* w_in     = (const float*)d_in[1];
    const float* b_in     = (const float*)d_in[2];
    const float* ln_in_g  = (const float*)d_in[3];
    const float* ln_in_b  = (const float*)d_in[4];
    const float* s4B      = (const float*)d_in[5];
    const float* s4C      = (const float*)d_in[6];
    const float* s4logdt  = (const float*)d_in[7];
    const float* s4D      = (const float*)d_in[8];
    const float* ln_g     = (const float*)d_in[9];
    const float* ln_b     = (const float*)d_in[10];
    const float* cls      = (const float*)d_in[11];
    const float* mha_in_w = (const float*)d_in[12];
    const float* mha_in_b = (const float*)d_in[13];
    const float* mha_out_w= (const float*)d_in[14];
    const float* mha_out_b= (const float*)d_in[15];
    const float* head_w1  = (const float*)d_in[16];
    const float* head_b1  = (const float*)d_in[17];
    const float* head_w2  = (const float*)d_in[18];
    const float* head_b2  = (const float*)d_in[19];

    float* ws   = (float*)d_ws;
    float* h    = ws + OFF_H;
    float* kker = ws + OFF_K;
    float* invn = ws + OFF_INV;
    float* P  = h;                 // 33 * 4096
    float* Q  = h + 540672;        // 32 * 4096
    float* Lb = h + 1064960;
    float* Rb = h + 3162112;
    float* qkb  = ws + OFF_MHA;
    float* qbb  = qkb + 2048;
    float* scb  = qbb + 16;        // 262144 floats; reused: whi/wlo (pre-embed), ctx1 (post-softmax)
    float* attb = scb + 262144;
    unsigned short* whi = (unsigned short*)scb;
    unsigned short* wlo = whi + 256 * 136;
    float* ctx1b = scb;            // 4*32*8*256 = 262144 floats, overlays dead scores

    k_build_ad<<<dim3(65), dim3(1024), 0, stream>>>(s4logdt, P, w_in, whi, wlo);
    for (int m = 1; m <= 5; ++m) {
        int half = 1 << (m - 1);
        k_mm64<<<dim3(half), dim3(256), 0, stream>>>(P, half, (m == 5) ? Q : nullptr);
    }
    for (int m = 1; m <= 5; ++m) {
        int half = 1 << (m - 1);
        int cnt = (m == 5) ? 15 : half;
        k_mm64<<<dim3(cnt), dim3(256), 0, stream>>>(Q, half, nullptr);
    }
    k_lr<<<dim3(NLY * 64), dim3(256), 0, stream>>>(P, Q, s4B, s4C, Lb, Rb);
    k_kker<<<dim3(NLY * 256), dim3(256), 0, stream>>>(Lb, Rb, kker);

    k_embed_mfma<<<dim3(16, BB), dim3(256), 0, stream>>>(x, whi, wlo, w_in, b_in,
                                                         ln_in_g, ln_in_b, h, invn);

    for (int l = 0; l < NLY; ++l) {
        k_conv32<<<dim3(DD), dim3(512), 0, stream>>>(h, kker, invn, s4D, l);
        k_ln<<<dim3(16, BB), dim3(256), 0, stream>>>(h, ln_g + l * DD, ln_b + l * DD, h, invn);
    }

    k_qprep<<<dim3(1), dim3(256), 0, stream>>>(cls, mha_in_w, mha_in_b, qkb, qbb);
    k_scores<<<dim3(8, BB), dim3(128), 0, stream>>>(h, cls, qkb, qbb, scb);
    k_softmax<<<dim3(256), dim3(256), 0, stream>>>(scb, attb);
    k_ctx1<<<dim3(8, 4, BB), dim3(256), 0, stream>>>(h, attb, ctx1b);
    k_head<<<dim3(BB), dim3(256), 0, stream>>>(ctx1b, attb, cls, mha_in_w, mha_in_b,
                                               mha_out_w, mha_out_b,
                                               head_w1, head_b1, head_w2, head_b2, (float*)d_out);
}

// Round 13
// 621.123 us; speedup vs baseline: 1.2659x; 1.0549x over previous
//
#include <hip/hip_runtime.h>

#define BB 32
#define CC 129
#define TT 1000
#define DD 256
#define NN 64
#define NLY 4

// ---------------- workspace layout (floats) ----------------
#define OFF_H    0
#define OFF_K    8192000
#define OFF_INV  9232384
#define OFF_MHA  9264384

typedef __attribute__((ext_vector_type(8))) short bf16x8;
typedef __attribute__((ext_vector_type(8))) _Float16 f16x8;
typedef __attribute__((ext_vector_type(4))) float f32x4;
typedef __attribute__((ext_vector_type(16))) float f32x16;

__device__ __forceinline__ unsigned short f2bf(float x) {
    unsigned int u = __float_as_uint(x);
    unsigned int r = (u + 0x7FFF + ((u >> 16) & 1)) >> 16;
    return (unsigned short)r;
}
__device__ __forceinline__ float bf2f(unsigned short b) {
    return __uint_as_float(((unsigned int)b) << 16);
}
__device__ __forceinline__ unsigned short f2h(float x) {
    _Float16 v = (_Float16)x;
    return *(unsigned short*)&v;
}
__device__ __forceinline__ float h2f(unsigned short b) {
    _Float16 v = *(_Float16*)&b;
    return (float)v;
}

// ============ Ad build (block 0) + w_in split-bf16 prep (blocks 1..64) ============
#define ST 131
__global__ __launch_bounds__(1024) void k_build_ad(const float* __restrict__ logdt,
                                                   float* __restrict__ P,
                                                   const float* __restrict__ w_in,
                                                   unsigned short* __restrict__ whi,
                                                   unsigned short* __restrict__ wlo) {
    __shared__ float M[64 * ST + 16];
    int tid = threadIdx.x;
    if (blockIdx.x != 0) {
        int d = (blockIdx.x - 1) * 4 + (tid >> 8);
        int c = tid & 255;
        if (c < 136) {
            float v = (c < CC) ? w_in[d * CC + c] : 0.f;
            unsigned short h = f2bf(v);
            whi[d * 136 + c] = h;
            wlo[d * 136 + c] = f2bf(v - bf2f(h));
        }
        return;
    }
    int q = tid >> 6, r = tid & 63;
    float dt = expf(logdt[0]);
    dt = fminf(fmaxf(dt, 1e-4f), 0.1f);
    float hh = dt * 0.5f;
    float Pr = sqrtf(1.f + 2.f * (float)r);
    for (int j = q; j < 130; j += 16) {
        if (j < 64) {
            float a;
            if (r == j) a = -((float)r + 0.5f);
            else { float m = Pr * sqrtf(1.f + 2.f * (float)j); a = (r > j) ? -m : m; }
            M[r * ST + j] = ((r == j) ? 1.f : 0.f) - hh * a;
        } else {
            M[r * ST + j] = (r == (j - 64)) ? 2.f : 0.f;
        }
    }
    __syncthreads();
    for (int c = 0; c < 64; ++c) {
        float invp = 1.f / M[c * ST + c];
        float f = M[r * ST + c] * invp;
        if (r != c) {
            int j0 = (c + 1) + ((q - (c + 1)) & 15);
            const float* prow = &M[c * ST];
            float* mrow = &M[r * ST];
            for (int j = j0; j < 130; j += 16)
                mrow[j] = fmaf(-f, prow[j], mrow[j]);
        }
        __syncthreads();
    }
    float invd = 1.f / M[r * ST + r];
    for (int j = q; j < 64; j += 16) {
        P[r * 64 + j] = (r == j) ? 1.f : 0.f;
        P[4096 + r * 64 + j] = M[r * ST + 64 + j] * invd - ((r == j) ? 1.f : 0.f);
    }
}

// ============ power-tree matmul; optional Q0/Q1 fold-in on the j==32 block ============
__global__ __launch_bounds__(256) void k_mm64(float* __restrict__ base, int half,
                                              float* __restrict__ qdst) {
    __shared__ float As[4096], Bs[4096];
    int j = half + 1 + blockIdx.x;
    const float* Am = base + (size_t)half * 4096;
    const float* Bm = base + (size_t)(j - half) * 4096;
    float* Dm = base + (size_t)j * 4096;
    for (int i = threadIdx.x; i < 4096; i += 256) { As[i] = Am[i]; Bs[i] = Bm[i]; }
    __syncthreads();
    int tr = (threadIdx.x >> 4) << 2;
    int tc = (threadIdx.x & 15) << 2;
    float acc[4][4];
#pragma unroll
    for (int u = 0; u < 4; ++u)
#pragma unroll
        for (int v = 0; v < 4; ++v) acc[u][v] = 0.f;
    for (int k = 0; k < 64; ++k) {
        float a0 = As[(tr + 0) * 64 + k], a1 = As[(tr + 1) * 64 + k];
        float a2 = As[(tr + 2) * 64 + k], a3 = As[(tr + 3) * 64 + k];
        float b0 = Bs[k * 64 + tc + 0], b1 = Bs[k * 64 + tc + 1];
        float b2 = Bs[k * 64 + tc + 2], b3 = Bs[k * 64 + tc + 3];
        acc[0][0] = fmaf(a0, b0, acc[0][0]); acc[0][1] = fmaf(a0, b1, acc[0][1]);
        acc[0][2] = fmaf(a0, b2, acc[0][2]); acc[0][3] = fmaf(a0, b3, acc[0][3]);
        acc[1][0] = fmaf(a1, b0, acc[1][0]); acc[1][1] = fmaf(a1, b1, acc[1][1]);
        acc[1][2] = fmaf(a1, b2, acc[1][2]); acc[1][3] = fmaf(a1, b3, acc[1][3]);
        acc[2][0] = fmaf(a2, b0, acc[2][0]); acc[2][1] = fmaf(a2, b1, acc[2][1]);
        acc[2][2] = fmaf(a2, b2, acc[2][2]); acc[2][3] = fmaf(a2, b3, acc[2][3]);
        acc[3][0] = fmaf(a3, b0, acc[3][0]); acc[3][1] = fmaf(a3, b1, acc[3][1]);
        acc[3][2] = fmaf(a3, b2, acc[3][2]); acc[3][3] = fmaf(a3, b3, acc[3][3]);
    }
#pragma unroll
    for (int u = 0; u < 4; ++u)
#pragma unroll
        for (int v = 0; v < 4; ++v) Dm[(tr + u) * 64 + tc + v] = acc[u][v];
    if (qdst && j == 32) {
#pragma unroll
        for (int u = 0; u < 4; ++u)
#pragma unroll
            for (int v = 0; v < 4; ++v) {
                int rr = tr + u, cc = tc + v;
                qdst[rr * 64 + cc] = (rr == cc) ? 1.f : 0.f;
                qdst[4096 + rr * 64 + cc] = acc[u][v];
            }
    }
}

// ============ L / R ============
__global__ __launch_bounds__(256) void k_lr(const float* __restrict__ P, const float* __restrict__ Q,
                                            const float* __restrict__ s4B, const float* __restrict__ s4C,
                                            float* __restrict__ L, float* __restrict__ R) {
    __shared__ float Ms[4096];
    int l = blockIdx.x >> 6, rem = blockIdx.x & 63, which = rem >> 5, idx = rem & 31;
    const float* M = which ? (P + (size_t)idx * 4096)
                           : (Q + (size_t)idx * 4096);
    for (int i = threadIdx.x; i < 4096; i += 256) Ms[i] = M[i];
    __syncthreads();
    int d = threadIdx.x;
    if (which == 0) {
        float* dst = L + (((size_t)(l * DD + d) * 32 + idx) * 64);
        for (int jc = 0; jc < 8; ++jc) {
            float acc[8];
#pragma unroll
            for (int u = 0; u < 8; ++u) acc[u] = 0.f;
            for (int i = 0; i < 64; ++i) {
                float bv = s4B[(l * NN + i) * DD + d];
#pragma unroll
                for (int u = 0; u < 8; ++u)
                    acc[u] = fmaf(bv, Ms[i * 64 + jc * 8 + u], acc[u]);
            }
#pragma unroll
            for (int u = 0; u < 8; ++u) dst[jc * 8 + u] = acc[u];
        }
    } else {
        float* dst = R + (((size_t)(l * DD + d) * 32 + idx) * 64);
        const float* Cp = s4C + (size_t)(l * DD + d) * NN;
        for (int ic = 0; ic < 8; ++ic) {
            float acc[8];
#pragma unroll
            for (int u = 0; u < 8; ++u) acc[u] = 0.f;
            for (int j = 0; j < 64; ++j) {
                float cv = Cp[j];
#pragma unroll
                for (int u = 0; u < 8; ++u)
                    acc[u] = fmaf(Ms[(ic * 8 + u) * 64 + j], cv, acc[u]);
            }
#pragma unroll
            for (int u = 0; u < 8; ++u) dst[ic * 8 + u] = acc[u];
        }
    }
}

// ============ kernel assembly ============
__global__ __launch_bounds__(256) void k_kker(const float* __restrict__ L, const float* __restrict__ R,
                                              float* __restrict__ kk) {
    __shared__ float Ls[32 * 65], Rs[32 * 65];
    int l = blockIdx.x >> 8, d = blockIdx.x & 255;
    const float* Lp = L + ((size_t)(l * DD + d) * 32) * 64;
    const float* Rp = R + ((size_t)(l * DD + d) * 32) * 64;
    for (int i = threadIdx.x; i < 2048; i += 256) {
        int row = i >> 6, col = i & 63;
        Ls[row * 65 + col] = Lp[i];
        Rs[row * 65 + col] = Rp[i];
    }
    __syncthreads();
    for (int t = threadIdx.x; t < TT; t += 256) {
        int kq = t >> 5, r = t & 31;
        const float* lr = &Ls[kq * 65];
        const float* rr = &Rs[r * 65];
        float a = 0.f;
#pragma unroll 8
        for (int m = 0; m < 64; ++m) a = fmaf(lr[m], rr[m], a);
        kk[(size_t)(l * DD + d) * TT + t] = a * expf(-0.01f * (float)t);
    }
}

// ============ MFMA embed + fused LayerNorm + pos-encoding + invn ============
__global__ __launch_bounds__(256) void k_embed_mfma(const float* __restrict__ x,
                                                    const unsigned short* __restrict__ whi,
                                                    const unsigned short* __restrict__ wlo,
                                                    const float* __restrict__ w_in,
                                                    const float* __restrict__ b_in,
                                                    const float* __restrict__ lng,
                                                    const float* __restrict__ lnb,
                                                    float* __restrict__ h,
                                                    float* __restrict__ invn) {
    __shared__ unsigned short xs_h[64 * 130], xs_l[64 * 130];
    __shared__ float xlasts[64], w128s[256], biass[256], gs[256], bs[256];
    __shared__ float ps[64][16], ps2[64][16];
    __shared__ float mstat[64], rstat[64];
    int b = blockIdx.y, t0 = blockIdx.x * 64;
    int tid = threadIdx.x;
    for (int i = tid; i < CC * 64; i += 256) {
        int c = i >> 6, tl = i & 63;
        int t = t0 + tl;
        float v = (t < TT) ? x[(size_t)(b * CC + c) * TT + t] : 0.f;
        if (c == 128) {
            xlasts[tl] = v;
        } else {
            unsigned short hh = f2bf(v);
            xs_h[tl * 130 + c] = hh;
            xs_l[tl * 130 + c] = f2bf(v - bf2f(hh));
        }
    }
    w128s[tid] = w_in[tid * CC + 128];
    biass[tid] = b_in[tid];
    gs[tid] = lng[tid];
    bs[tid] = lnb[tid];
    __syncthreads();
    int wave = tid >> 6, lane = tid & 63;
    int tn = lane & 15, q = lane >> 4;
    int d0w = wave * 64;
    f32x4 acc[4][4];
#pragma unroll
    for (int nt = 0; nt < 4; ++nt)
#pragma unroll
        for (int mt = 0; mt < 4; ++mt) acc[nt][mt] = (f32x4){0.f, 0.f, 0.f, 0.f};
#pragma unroll
    for (int kc = 0; kc < 4; ++kc) {
        int c0 = kc * 32;
        bf16x8 Ah[4], Al[4];
#pragma unroll
        for (int mt = 0; mt < 4; ++mt) {
            int base = (d0w + mt * 16 + tn) * 136 + c0 + 8 * q;
            Ah[mt] = *(const bf16x8*)&whi[base];
            Al[mt] = *(const bf16x8*)&wlo[base];
        }
#pragma unroll
        for (int nt = 0; nt < 4; ++nt) {
            const unsigned int* ph = (const unsigned int*)&xs_h[(nt * 16 + tn) * 130 + c0 + 8 * q];
            const unsigned int* pl = (const unsigned int*)&xs_l[(nt * 16 + tn) * 130 + c0 + 8 * q];
            union { bf16x8 v; unsigned int u[4]; } Bh, Bl;
            Bh.u[0] = ph[0]; Bh.u[1] = ph[1]; Bh.u[2] = ph[2]; Bh.u[3] = ph[3];
            Bl.u[0] = pl[0]; Bl.u[1] = pl[1]; Bl.u[2] = pl[2]; Bl.u[3] = pl[3];
#pragma unroll
            for (int mt = 0; mt < 4; ++mt) {
                acc[nt][mt] = __builtin_amdgcn_mfma_f32_16x16x32_bf16(Al[mt], Bh.v, acc[nt][mt], 0, 0, 0);
                acc[nt][mt] = __builtin_amdgcn_mfma_f32_16x16x32_bf16(Ah[mt], Bl.v, acc[nt][mt], 0, 0, 0);
                acc[nt][mt] = __builtin_amdgcn_mfma_f32_16x16x32_bf16(Ah[mt], Bh.v, acc[nt][mt], 0, 0, 0);
            }
        }
    }
#pragma unroll
    for (int nt = 0; nt < 4; ++nt) {
        float xl = xlasts[nt * 16 + tn];
        float s = 0.f, s2 = 0.f;
#pragma unroll
        for (int mt = 0; mt < 4; ++mt) {
#pragma unroll
            for (int r = 0; r < 4; ++r) {
                int d = d0w + mt * 16 + 4 * q + r;
                float v = acc[nt][mt][r] + biass[d] + w128s[d] * xl;
                acc[nt][mt][r] = v;
                s += v; s2 = fmaf(v, v, s2);
            }
        }
        ps[nt * 16 + tn][wave * 4 + q] = s;
        ps2[nt * 16 + tn][wave * 4 + q] = s2;
    }
    __syncthreads();
    if (tid < 64) {
        float s = 0.f, s2 = 0.f;
#pragma unroll
        for (int k = 0; k < 16; ++k) { s += ps[tid][k]; s2 += ps2[tid][k]; }
        float mean = s * (1.f / 256.f);
        float ex2 = s2 * (1.f / 256.f);
        mstat[tid] = mean;
        rstat[tid] = 1.f / sqrtf(ex2 - mean * mean + 1e-5f);
    }
    __syncthreads();
#pragma unroll
    for (int nt = 0; nt < 4; ++nt) {
        int tl = nt * 16 + tn;
        int t = t0 + tl;
        float mean = mstat[tl], rstd = rstat[tl];
        float ft = (float)t;
        float sq = 0.f;
#pragma unroll
        for (int mt = 0; mt < 4; ++mt) {
#pragma unroll
            for (int r = 0; r < 4; ++r) {
                int d = d0w + mt * 16 + 4 * q + r;
                float o = (acc[nt][mt][r] - mean) * rstd * gs[d] + bs[d];
                float freq = expf((float)(d & ~1) * (-9.210340371976184f / 256.f));
                float ang = ft * freq;
                o += (d & 1) ? cosf(ang) : sinf(ang);
                if (t < TT) h[((size_t)(b * DD + d)) * TT + t] = o;
                sq = fmaf(o, o, sq);
            }
        }
        ps[tl][wave * 4 + q] = sq;
    }
    __syncthreads();
    if (tid < 64) {
        int t = t0 + tid;
        if (t < TT) {
            float s = 0.f;
#pragma unroll
            for (int k = 0; k < 16; ++k) s += ps[tid][k];
            invn[b * TT + t] = 1.f / (sqrtf(s) + 1e-8f);
        }
    }
}

// ============ LayerNorm (in-place), single-pass ============
__global__ __launch_bounds__(256) void k_ln(const float* __restrict__ in, const float* __restrict__ g,
                                            const float* __restrict__ bia, float* __restrict__ out,
                                            float* __restrict__ invn) {
    int b = blockIdx.y, t0 = blockIdx.x * 64;
    int w = threadIdx.x >> 6, lane = threadIdx.x & 63;
    int t = t0 + lane;
    __shared__ float ps[4][64], ps2[4][64];
    float v[64];
    float s = 0.f, s2 = 0.f;
    bool ok = t < TT;
#pragma unroll
    for (int k = 0; k < 64; ++k) {
        float x = ok ? in[(size_t)(b * DD + (w + 4 * k)) * TT + t] : 0.f;
        v[k] = x;
        s += x; s2 = fmaf(x, x, s2);
    }
    ps[w][lane] = s; ps2[w][lane] = s2;
    __syncthreads();
    float mean = (ps[0][lane] + ps[1][lane] + ps[2][lane] + ps[3][lane]) * (1.f / 256.f);
    float ex2  = (ps2[0][lane] + ps2[1][lane] + ps2[2][lane] + ps2[3][lane]) * (1.f / 256.f);
    float rstd = 1.f / sqrtf(ex2 - mean * mean + 1e-5f);
    float sq = 0.f;
    if (ok) {
#pragma unroll
        for (int k = 0; k < 64; ++k) {
            int d = w + 4 * k;
            float o = (v[k] - mean) * rstd * g[d] + bia[d];
            out[(size_t)(b * DD + d) * TT + t] = o;
            sq = fmaf(o, o, sq);
        }
    }
    __syncthreads();
    ps[w][lane] = sq;
    __syncthreads();
    if (w == 0 && ok) {
        float tot = ps[0][lane] + ps[1][lane] + ps[2][lane] + ps[3][lane];
        invn[b * TT + t] = 1.f / (sqrtf(tot) + 1e-8f);
    }
}

__device__ __forceinline__ float gelu_exact(float y) {
    return 0.5f * y * (1.f + erff(y * 0.7071067811865476f));
}

// ============ MFMA conv, 32x32x16 fp16 single (1 MFMA/slab), one block per d ============
// fp16 rounding error is incoherent over K~1000 terms -> conv-out error ~2.5e-5/layer
// (vs 1.35e-3 threshold). Residual ho RE-READ from global (L2-hot) — reconstructing
// it from rounded fp16 would inject 2.4e-4/layer, the only dangerous path.
// Toeplitz B: pair-packed dwords pk[m]=(k~[m]|k~[m-1]) -> 4 aligned b32 per frag.
// A: contiguous fp16 b128. Snake: wave w does groups {w, 15-w} -> 68 D-steps.
#define XS2 1032
__global__ __launch_bounds__(512) void k_conv32(float* __restrict__ h, const float* __restrict__ kk,
                                                const float* __restrict__ invn,
                                                const float* __restrict__ s4D, int layer) {
    __shared__ unsigned short Xs[32 * XS2];
    __shared__ unsigned int pks[1056];
    int d = blockIdx.x;
    int tid = threadIdx.x;
    const float* krow = kk + (size_t)(layer * DD + d) * TT;
    for (int mm = tid; mm < 1056; mm += 512) {
        int m = mm - 32;
        float klo = (m >= 0 && m < TT) ? krow[m] : 0.f;
        float kpr = (m >= 1 && m <= TT) ? krow[m - 1] : 0.f;
        pks[mm] = (unsigned int)f2h(klo) | ((unsigned int)f2h(kpr) << 16);
    }
    for (int ii = tid; ii < 32 * 512; ii += 512) {
        int bb = ii >> 9;
        int tp = (ii & 511) * 2;
        const float* hrow = h + ((size_t)bb * DD + d) * TT;
        const float* ivr = invn + (size_t)bb * TT;
        float v0 = (tp < TT) ? hrow[tp] * ivr[tp] : 0.f;
        float v1 = (tp + 1 < TT) ? hrow[tp + 1] * ivr[tp + 1] : 0.f;
        ((unsigned int*)Xs)[(bb * XS2 + tp) >> 1] = (unsigned int)f2h(v0) | ((unsigned int)f2h(v1) << 16);
    }
    __syncthreads();
    float gate = 1.f / (1.f + expf(-s4D[layer * DD + d]));
    int wave = tid >> 6, lane = tid & 63;
    int nn = lane & 31, kq8 = (lane >> 5) << 3;
    for (int pass = 0; pass < 2; ++pass) {
        int G = pass ? (15 - wave) : wave;
        int jlo = 2 * G;
        f32x16 acc[2];
#pragma unroll
        for (int m = 0; m < 2; ++m)
#pragma unroll
            for (int r = 0; r < 16; ++r) acc[m][r] = 0.f;
        for (int D = 32 * jlo + 32; D >= -16; D -= 16) {
            int S32 = D + nn - kq8 + 32;
            union { f16x8 v; unsigned int u[4]; } bh;
            bh.u[0] = pks[S32];
            bh.u[1] = pks[S32 - 2];
            bh.u[2] = pks[S32 - 4];
            bh.u[3] = pks[S32 - 6];
#pragma unroll
            for (int m = 0; m < 2; ++m) {
                int u0 = (jlo + m) * 32 - D;
                if (u0 >= 0) {
                    const f16x8 ah = *(const f16x8*)&Xs[nn * XS2 + u0 + kq8];
                    acc[m] = __builtin_amdgcn_mfma_f32_32x32x16_f16(ah, bh.v, acc[m], 0, 0, 0);
                }
            }
        }
#pragma unroll
        for (int m = 0; m < 2; ++m) {
            int t = (jlo + m) * 32 + nn;
            if (t < TT) {
#pragma unroll
                for (int r = 0; r < 16; ++r) {
                    int brow = (r & 3) + 8 * (r >> 2) + 4 * (lane >> 5);
                    size_t ix = ((size_t)brow * DD + d) * TT + t;
                    float y = acc[m][r];
                    float xn = h2f(Xs[brow * XS2 + t]);
                    float ho = h[ix];                       // L2-hot re-read (exact residual)
                    h[ix] = gelu_exact(y + xn * gate) + 1.1f * ho;
                }
            }
        }
    }
}

// ============ MHA pooling ============
__global__ __launch_bounds__(256) void k_qprep(const float* __restrict__ cls, const float* __restrict__ inw,
                                               const float* __restrict__ inb, float* __restrict__ qk,
                                               float* __restrict__ qb) {
    __shared__ float Qv[256];
    int j = threadIdx.x;
    float a = inb[j];
    for (int i = 0; i < 256; ++i) a = fmaf(inw[j * DD + i], cls[i], a);
    Qv[j] = a;
    __syncthreads();
    const float scale = 0.17677669529663687f; // 1/sqrt(32)
    for (int idx = threadIdx.x; idx < 8 * 256; idx += 256) {
        int hh = idx >> 8, i = idx & 255;
        float s = 0.f;
        for (int jj = 0; jj < 32; ++jj)
            s = fmaf(Qv[hh * 32 + jj], inw[(DD + hh * 32 + jj) * DD + i], s);
        qk[idx] = s * scale;
    }
    if (threadIdx.x < 8) {
        int hh = threadIdx.x;
        float s = 0.f;
        for (int jj = 0; jj < 32; ++jj)
            s = fmaf(Qv[hh * 32 + jj], inb[DD + hh * 32 + jj], s);
        qb[hh] = s * scale;
    }
}

__global__ __launch_bounds__(128) void k_scores(const float* __restrict__ h, const float* __restrict__ cls,
                                                const float* __restrict__ qkw, const float* __restrict__ qbw,
                                                float* __restrict__ sc) {
    __shared__ float qks[8 * 256];
    int b = blockIdx.y;
    int s = blockIdx.x * 128 + threadIdx.x;
    for (int i = threadIdx.x; i < 2048; i += 128) qks[i] = qkw[i];
    __syncthreads();
    if (s >= TT + 1) return;
    float acc[8];
#pragma unroll
    for (int hh = 0; hh < 8; ++hh) acc[hh] = qbw[hh];
    if (s == 0) {
        for (int i = 0; i < 256; ++i) {
            float v = cls[i];
#pragma unroll
            for (int hh = 0; hh < 8; ++hh) acc[hh] = fmaf(qks[hh * 256 + i], v, acc[hh]);
        }
    } else {
        const float* hb = h + (size_t)b * DD * TT + (s - 1);
        for (int i = 0; i < 256; ++i) {
            float v = hb[(size_t)i * TT];
#pragma unroll
            for (int hh = 0; hh < 8; ++hh) acc[hh] = fmaf(qks[hh * 256 + i], v, acc[hh]);
        }
    }
#pragma unroll
    for (int hh = 0; hh < 8; ++hh) sc[(size_t)(b * 8 + hh) * 1024 + s] = acc[hh];
}

__global__ __launch_bounds__(256) void k_softmax(const float* __restrict__ sc, float* __restrict__ att) {
    int row = blockIdx.x;
    const float* p = sc + (size_t)row * 1024;
    float* o = att + (size_t)row * 1024;
    __shared__ float red[256];
    float m = -3.4e38f;
    for (int s = threadIdx.x; s < TT + 1; s += 256) m = fmaxf(m, p[s]);
    red[threadIdx.x] = m; __syncthreads();
    for (int st = 128; st; st >>= 1) {
        if (threadIdx.x < st) red[threadIdx.x] = fmaxf(red[threadIdx.x], red[threadIdx.x + st]);
        __syncthreads();
    }
    m = red[0]; __syncthreads();
    float sum = 0.f;
    for (int s = threadIdx.x; s < TT + 1; s += 256) {
        float e = expf(p[s] - m);
        o[s] = e; sum += e;
    }
    red[threadIdx.x] = sum; __syncthreads();
    for (int st = 128; st; st >>= 1) {
        if (threadIdx.x < st) red[threadIdx.x] += red[threadIdx.x + st];
        __syncthreads();
    }
    float inv = 1.f / red[0];
    for (int s = threadIdx.x; s < TT + 1; s += 256) o[s] *= inv;
}

// ============ ctx stage 1: t-chunked partials ============
__global__ __launch_bounds__(256) void k_ctx1(const float* __restrict__ h,
                                              const float* __restrict__ att,
                                              float* __restrict__ ctx1) {
    __shared__ float as[8][256];
    int i0 = blockIdx.x * 32, tc = blockIdx.y, b = blockIdx.z;
    int tid = threadIdx.x;
    int sbase = tc * 250 + 1;
    for (int idx = tid; idx < 2048; idx += 256) {
        int hh = idx >> 8, u = idx & 255;
        as[hh][u] = (u < 250) ? att[(size_t)(b * 8 + hh) * 1024 + sbase + u] : 0.f;
    }
    __syncthreads();
    int w = tid >> 6, lane = tid & 63;
    for (int ii = 0; ii < 8; ++ii) {
        int i = i0 + w * 8 + ii;
        const float* hb = h + ((size_t)(b * DD + i)) * TT + tc * 250;
        float acc[8];
#pragma unroll
        for (int hh = 0; hh < 8; ++hh) acc[hh] = 0.f;
        for (int u = lane; u < 250; u += 64) {
            float v = hb[u];
#pragma unroll
            for (int hh = 0; hh < 8; ++hh) acc[hh] = fmaf(as[hh][u], v, acc[hh]);
        }
#pragma unroll
        for (int off = 32; off; off >>= 1)
#pragma unroll
            for (int hh = 0; hh < 8; ++hh) acc[hh] += __shfl_down(acc[hh], off);
        if (lane == 0) {
#pragma unroll
            for (int hh = 0; hh < 8; ++hh)
                ctx1[(((size_t)tc * BB + b) * 8 + hh) * DD + i] = acc[hh];
        }
    }
}

// ============ head: reduce ctx partials + cls term, then MLP ============
__global__ __launch_bounds__(256) void k_head(const float* __restrict__ ctx1,
                                              const float* __restrict__ att,
                                              const float* __restrict__ cls,
                                              const float* __restrict__ inw,
                                              const float* __restrict__ inb, const float* __restrict__ outw,
                                              const float* __restrict__ outb, const float* __restrict__ w1,
                                              const float* __restrict__ b1, const float* __restrict__ w2,
                                              const float* __restrict__ b2, float* __restrict__ out) {
    int b = blockIdx.x;
    __shared__ float cs[2048], ao[256], po[256], hid[128];
    int j = threadIdx.x;
    {
        float cv = cls[j];
#pragma unroll
        for (int hh = 0; hh < 8; ++hh) {
            float a = att[(size_t)(b * 8 + hh) * 1024] * cv;
#pragma unroll
            for (int tc = 0; tc < 4; ++tc)
                a += ctx1[(((size_t)tc * BB + b) * 8 + hh) * DD + j];
            cs[hh * 256 + j] = a;
        }
    }
    __syncthreads();
    {
        int hh = j >> 5;
        float a = inb[2 * DD + j];
        const float* wv = inw + (size_t)(2 * DD + j) * DD;
        for (int i = 0; i < 256; ++i) a = fmaf(wv[i], cs[hh * 256 + i], a);
        ao[j] = a;
    }
    __syncthreads();
    {
        float a = outb[j];
        for (int i = 0; i < 256; ++i) a = fmaf(outw[j * DD + i], ao[i], a);
        po[j] = a;
    }
    __syncthreads();
    if (j < 128) {
        float a = b1[j];
        for (int i = 0; i < 256; ++i) a = fmaf(w1[j * 256 + i], po[i], a);
        hid[j] = fmaxf(a, 0.f);
    }
    __syncthreads();
    if (j == 0) {
        float a = b2[0];
        for (int i = 0; i < 128; ++i) a = fmaf(w2[i], hid[i], a);
        out[b] = a;
    }
}

extern "C" void kernel_launch(void* const* d_in, const int* in_sizes, int n_in,
                              void* d_out, int out_size, void* d_ws, size_t ws_size,
                              hipStream_t stream) {
    (void)in_sizes; (void)n_in; (void)out_size; (void)ws_size;
    const float* x        = (const float*)d_in[0];
    const float* w_in     = (const float*)d_in[1];
    const float* b_in     = (const float*)d_in[2];
    const float* ln_in_g  = (const float*)d_in[3];
    const float* ln_in_b  = (const float*)d_in[4];
    const float* s4B      = (const float*)d_in[5];
    const float* s4C      = (const float*)d_in[6];
    const float* s4logdt  = (const float*)d_in[7];
    const float* s4D      = (const float*)d_in[8];
    const float* ln_g     = (const float*)d_in[9];
    const float* ln_b     = (const float*)d_in[10];
    const float* cls      = (const float*)d_in[11];
    const float* mha_in_w = (const float*)d_in[12];
    const float* mha_in_b = (const float*)d_in[13];
    const float* mha_out_w= (const float*)d_in[14];
    const float* mha_out_b= (const float*)d_in[15];
    const float* head_w1  = (const float*)d_in[16];
    const float* head_b1  = (const float*)d_in[17];
    const float* head_w2  = (const float*)d_in[18];
    const float* head_b2  = (const float*)d_in[19];

    float* ws   = (float*)d_ws;
    float* h    = ws + OFF_H;
    float* kker = ws + OFF_K;
    float* invn = ws + OFF_INV;
    float* P  = h;                 // 33 * 4096
    float* Q  = h + 540672;        // 32 * 4096
    float* Lb = h + 1064960;
    float* Rb = h + 3162112;
    float* qkb  = ws + OFF_MHA;
    float* qbb  = qkb + 2048;
    float* scb  = qbb + 16;        // reused: whi/wlo (pre-embed), ctx1 (post-softmax)
    float* attb = scb + 262144;
    unsigned short* whi = (unsigned short*)scb;
    unsigned short* wlo = whi + 256 * 136;
    float* ctx1b = scb;

    k_build_ad<<<dim3(65), dim3(1024), 0, stream>>>(s4logdt, P, w_in, whi, wlo);
    for (int m = 1; m <= 5; ++m) {
        int half = 1 << (m - 1);
        k_mm64<<<dim3(half), dim3(256), 0, stream>>>(P, half, (m == 5) ? Q : nullptr);
    }
    for (int m = 1; m <= 5; ++m) {
        int half = 1 << (m - 1);
        int cnt = (m == 5) ? 15 : half;
        k_mm64<<<dim3(cnt), dim3(256), 0, stream>>>(Q, half, nullptr);
    }
    k_lr<<<dim3(NLY * 64), dim3(256), 0, stream>>>(P, Q, s4B, s4C, Lb, Rb);
    k_kker<<<dim3(NLY * 256), dim3(256), 0, stream>>>(Lb, Rb, kker);

    k_embed_mfma<<<dim3(16, BB), dim3(256), 0, stream>>>(x, whi, wlo, w_in, b_in,
                                                         ln_in_g, ln_in_b, h, invn);

    for (int l = 0; l < NLY; ++l) {
        k_conv32<<<dim3(DD), dim3(512), 0, stream>>>(h, kker, invn, s4D, l);
        k_ln<<<dim3(16, BB), dim3(256), 0, stream>>>(h, ln_g + l * DD, ln_b + l * DD, h, invn);
    }

    k_qprep<<<dim3(1), dim3(256), 0, stream>>>(cls, mha_in_w, mha_in_b, qkb, qbb);
    k_scores<<<dim3(8, BB), dim3(128), 0, stream>>>(h, cls, qkb, qbb, scb);
    k_softmax<<<dim3(256), dim3(256), 0, stream>>>(scb, attb);
    k_ctx1<<<dim3(8, 4, BB), dim3(256), 0, stream>>>(h, attb, ctx1b);
    k_head<<<dim3(BB), dim3(256), 0, stream>>>(ctx1b, attb, cls, mha_in_w, mha_in_b,
                                               mha_out_w, mha_out_b,
                                               head_w1, head_b1, head_w2, head_b2, (float*)d_out);
}